// Round 6
// baseline (534.199 us; speedup 1.0000x reference)
//
#include <hip/hip_runtime.h>

typedef unsigned short u16;
typedef __attribute__((ext_vector_type(8))) short short8;   // 8 bf16 = 4 VGPRs
typedef __attribute__((ext_vector_type(4))) float f32x4;
typedef __attribute__((ext_vector_type(4))) unsigned int u32x4;  // NT-capable uint4

#define NQn 100000
#define NAn 200000
#define E1n 250000
#define E2n 250000
#define E3n 500000
#define NLn 100000
#define SLOTS 40   // max in-degree bucket capacity; Poisson(5) => P(>40) ~ 1e-22

__device__ __forceinline__ float bf2f(u16 u) {
    return __uint_as_float(((unsigned)u) << 16);
}
__device__ __forceinline__ float bf2f_lo(unsigned u) {
    return __uint_as_float(u << 16);
}
__device__ __forceinline__ float bf2f_hi(unsigned u) {
    return __uint_as_float(u & 0xffff0000u);
}
__device__ __forceinline__ u16 f2bf(float f) {
    unsigned x = __float_as_uint(f);
    unsigned r = (x + 0x7fffu + ((x >> 16) & 1u)) >> 16;
    return (u16)r;
}
__device__ __forceinline__ float sigmoidf_(float x) {
    return 1.f / (1.f + __expf(-x));
}

// -------- fold per-relation transforms into K/V weights, OUTPUT IN MFMA ----
// -------- FRAGMENT LAYOUT ---------------------------------------------------
// Logical Wbig cols: [0,64): Wq ; [64,128): Wk@A(t0) ; [128,192): Wv@M(t0) ;
//                    [192,256): Wk@A(t1) ; [256,320): Wv@M(t1)
// Fragment layout: Wbigf[(((k>>5)*NT + (col>>4))*64 + ((k&31)>>3)*16 + (col&15))*8 + (k&7)]
__global__ void fold_kernel(
    const float* __restrict__ Wk, const float* __restrict__ Wv, const float* __restrict__ Wq,
    const float* __restrict__ bk, const float* __restrict__ bv, const float* __restrict__ bq,
    const float* __restrict__ a_rel, const float* __restrict__ m_rel,
    int t0, int t1, u16* __restrict__ Wbigf, float* __restrict__ bbig, int NOUT)
{
    const int NT = NOUT >> 4;
    const int total = 65 * NOUT;   // 64 weight rows + 1 bias row
    for (int idx = blockIdx.x * blockDim.x + threadIdx.x; idx < total;
         idx += gridDim.x * blockDim.x) {
        const int c   = idx / NOUT;
        const int col = idx - c * NOUT;
        const int grp = col >> 6;
        const int oc  = col & 63;
        const int h   = oc >> 5, e = oc & 31;
        if (c < 64) {
            float val;
            if (grp == 0) {
                val = Wq[c * 64 + oc];
            } else {
                const int t = (grp <= 2) ? t0 : t1;
                const float* W = (grp & 1) ? Wk : Wv;
                const float* T = (grp & 1) ? a_rel : m_rel;
                float s = 0.f;
                for (int d = 0; d < 32; ++d)
                    s = fmaf(W[c * 64 + h * 32 + d],
                             T[((t * 2 + h) * 32 + d) * 32 + e], s);
                val = s;
            }
            const int fi = (((c >> 5) * NT + (col >> 4)) * 64
                            + ((c & 31) >> 3) * 16 + (col & 15)) * 8 + (c & 7);
            Wbigf[fi] = f2bf(val);
        } else {
            float val;
            if (grp == 0) {
                val = bq[oc];
            } else {
                const int t = (grp <= 2) ? t0 : t1;
                const float* B = (grp & 1) ? bk : bv;
                const float* T = (grp & 1) ? a_rel : m_rel;
                float s = 0.f;
                for (int d = 0; d < 32; ++d)
                    s = fmaf(B[h * 32 + d],
                             T[((t * 2 + h) * 32 + d) * 32 + e], s);
                val = s;
            }
            bbig[col] = val;
        }
    }
}

// -------- fold [K x 64] f32 weights into MFMA fragment layout (bf16) -------
// Wf[(f*64+ln)*8+j] = W[(kt*32+(ln>>4)*8+j)*64 + nt*16+(ln&15)], f=kt*4+nt.
// Handles Win_q (K=128), Win_a (K=128), Wo_an (K=64), Wo_qn (K=64) in one launch.
__global__ void fold_small(
    const float* __restrict__ Winq, u16* __restrict__ Winfq,
    const float* __restrict__ Wina, u16* __restrict__ Winfa,
    const float* __restrict__ WoA, u16* __restrict__ WofA,
    const float* __restrict__ WoQ, u16* __restrict__ WofQ)
{
    const int gid = blockIdx.x * 256 + threadIdx.x;
    const float* W; u16* Wf; int t;
    if (gid < 8192)        { W = Winq; Wf = Winfq; t = gid; }
    else if (gid < 16384)  { W = Wina; Wf = Winfa; t = gid - 8192; }
    else if (gid < 20480)  { W = WoA;  Wf = WofA;  t = gid - 16384; }
    else if (gid < 24576)  { W = WoQ;  Wf = WofQ;  t = gid - 20480; }
    else return;
    const int j = t & 7, ln = (t >> 3) & 63, f = t >> 9;
    const int kt = f >> 2, nt = f & 3;
    const int k = kt * 32 + (ln >> 4) * 8 + j;
    const int n = nt * 16 + (ln & 15);
    Wf[t] = f2bf(W[k * 64 + n]);
}

// -------- MFMA fused node projection --------------------------------------
// r5/r6: non-temporal streaming. r4 post-mortem: at 37% occupancy the
// in-flight output tiles exceed per-XCD L2 => partially-combined lines
// evicted + RMW re-fetched (FETCH/WRITE each inflated ~+80 MB). x is read
// once, h/big are consumed only much later => NT loads/stores end the thrash.
// (r5 compile fix: NT builtins need ext_vector types, not HIP_vector_type.)
template <int NOUT>
__global__ __launch_bounds__(256, 4) void node_mfma(
    const float* __restrict__ x, int N,
    const u16* __restrict__ Winf, const float* __restrict__ bin,
    const u16* __restrict__ Wbigf, const float* __restrict__ bbig,
    u16* __restrict__ h_out, u16* __restrict__ big_out)
{
    constexpr int NT = NOUT / 16;            // stage-2 col tiles
    constexpr int NG = NT / 4;               // stage-2 64-col store groups
    __shared__ __align__(16) short sB2[2 * NT * 64 * 8];  // [kt2][nt][lane][j]
    __shared__ __align__(16) short sH[4][16 * 72];        // per-wave tile, stride 72

    const int tid = threadIdx.x;
    for (int idx = tid; idx < 2 * NT * 64; idx += 256)
        ((u32x4*)sB2)[idx] = ((const u32x4*)Wbigf)[idx];
    __syncthreads();

    const int wave = tid >> 6;
    const int lane = tid & 63;
    const int quad = lane >> 4;
    const int mrow = lane & 15;
    short* const myH = &sH[wave][0];
    const int srow = lane >> 2;              // store-phase row
    const int scol = (lane & 3) * 16;        // store-phase col base

    // stage-1 B fragments in registers (16 x short8 = 64 VGPR), coalesced loads
    short8 wb1[16];
    #pragma unroll
    for (int f = 0; f < 16; ++f)
        wb1[f] = *(const short8*)&Winf[(f * 64 + lane) * 8];
    float bin4[4];
    #pragma unroll
    for (int nt = 0; nt < 4; ++nt) bin4[nt] = bin[nt * 16 + mrow];

    const int ntiles = (N + 63) >> 6;
    for (int tile = blockIdx.x; tile < ntiles; tile += gridDim.x) {
        const int nbase = tile * 64 + wave * 16;
        const int node = nbase + mrow;
        const bool fullgrp = (nbase + 16 <= N);

        short8 a1[4];
        if (node < N) {
            const float* xp = x + (size_t)node * 128 + quad * 8;
            #pragma unroll
            for (int kt = 0; kt < 4; ++kt) {
                const f32x4 u0 = __builtin_nontemporal_load((const f32x4*)(xp + kt * 32));
                const f32x4 u1 = __builtin_nontemporal_load((const f32x4*)(xp + kt * 32 + 4));
                short8 f;
                f[0] = (short)f2bf(u0.x); f[1] = (short)f2bf(u0.y);
                f[2] = (short)f2bf(u0.z); f[3] = (short)f2bf(u0.w);
                f[4] = (short)f2bf(u1.x); f[5] = (short)f2bf(u1.y);
                f[6] = (short)f2bf(u1.z); f[7] = (short)f2bf(u1.w);
                a1[kt] = f;
            }
        } else {
            #pragma unroll
            for (int kt = 0; kt < 4; ++kt) a1[kt] = short8{0,0,0,0,0,0,0,0};
        }

        // ---- stage 1: h = relu(x@Win + b1) -> myH ----
        #pragma unroll
        for (int nt = 0; nt < 4; ++nt) {
            const float bv = bin4[nt];
            f32x4 acc = {bv, bv, bv, bv};
            #pragma unroll
            for (int kt = 0; kt < 4; ++kt)
                acc = __builtin_amdgcn_mfma_f32_16x16x32_bf16(a1[kt], wb1[kt * 4 + nt],
                                                              acc, 0, 0, 0);
            #pragma unroll
            for (int r = 0; r < 4; ++r)
                myH[(quad * 4 + r) * 72 + nt * 16 + mrow] =
                    (short)f2bf(fmaxf(acc[r], 0.f));
        }

        // ---- coalesced h store: 16 rows x 128 B = 2 KB contiguous (NT) ----
        if (fullgrp) {
            const u32x4 w0 = *(const u32x4*)&myH[srow * 72 + scol];
            const u32x4 w1 = *(const u32x4*)&myH[srow * 72 + scol + 8];
            __builtin_nontemporal_store(w0, (u32x4*)(h_out + (size_t)nbase * 64 + (size_t)lane * 16));
            __builtin_nontemporal_store(w1, (u32x4*)(h_out + (size_t)nbase * 64 + (size_t)lane * 16 + 8));
        } else {
            for (int e = lane; e < 16 * 64; e += 64) {
                const int r = e >> 6, c = e & 63;
                const int nd = nbase + r;
                if (nd < N) h_out[(size_t)nd * 64 + c] = (u16)myH[r * 72 + c];
            }
        }

        // ---- stage 2: big = h @ Wbig + b2, grouped 64-col staging ----
        short8 a2[2];
        #pragma unroll
        for (int kt2 = 0; kt2 < 2; ++kt2)
            a2[kt2] = *(const short8*)&myH[mrow * 72 + kt2 * 32 + quad * 8];

        #pragma unroll
        for (int g = 0; g < NG; ++g) {
            #pragma unroll
            for (int q2 = 0; q2 < 4; ++q2) {
                const int nt = g * 4 + q2;
                const float bv = bbig[nt * 16 + mrow];
                f32x4 acc = {bv, bv, bv, bv};
                const short8 b0 = *(const short8*)&sB2[((0 * NT + nt) * 64 + lane) * 8];
                acc = __builtin_amdgcn_mfma_f32_16x16x32_bf16(a2[0], b0, acc, 0, 0, 0);
                const short8 b1 = *(const short8*)&sB2[((1 * NT + nt) * 64 + lane) * 8];
                acc = __builtin_amdgcn_mfma_f32_16x16x32_bf16(a2[1], b1, acc, 0, 0, 0);
                #pragma unroll
                for (int r = 0; r < 4; ++r)
                    myH[(quad * 4 + r) * 72 + q2 * 16 + mrow] = (short)f2bf(acc[r]);
            }
            if (fullgrp) {
                const u32x4 w0 = *(const u32x4*)&myH[srow * 72 + scol];
                const u32x4 w1 = *(const u32x4*)&myH[srow * 72 + scol + 8];
                u16* dst = big_out + (size_t)(nbase + srow) * NOUT + g * 64 + scol;
                __builtin_nontemporal_store(w0, (u32x4*)dst);
                __builtin_nontemporal_store(w1, (u32x4*)(dst + 8));
            } else {
                for (int e = lane; e < 16 * 64; e += 64) {
                    const int r = e >> 6, c = e & 63;
                    const int nd = nbase + r;
                    if (nd < N)
                        big_out[(size_t)nd * NOUT + g * 64 + c] = (u16)myH[r * 72 + c];
                }
            }
        }
    }
}

// -------- merged scatter: bucket all 3 relations in one launch -------------
// payload.x = (src*srcStride + kBase) | relBit   (k-offset, mult of 32; v = +64)
// payload.y = bits of per-edge weight w
__global__ __launch_bounds__(256) void scatter_all(
    const int* __restrict__ ei1, const int* __restrict__ ei2, const int* __restrict__ ei3,
    const float* __restrict__ w1, const float* __restrict__ w2, const float* __restrict__ w3,
    int* __restrict__ cursor_a, int* __restrict__ cursor_q,
    int2* __restrict__ payload_a, int2* __restrict__ payload_q)
{
    const int gid = blockIdx.x * 256 + threadIdx.x;
    const int* src; const int* dst; const float* w;
    int e, stride, kbase, rel; int* cur; int2* pay;
    if (gid < E1n) {
        e = gid; src = ei1; dst = ei1 + E1n; w = w1;
        stride = 320; kbase = 64; rel = 0; cur = cursor_a; pay = payload_a;
    } else if (gid < E1n + E2n) {
        e = gid - E1n; src = ei2; dst = ei2 + E2n; w = w2;
        stride = 320; kbase = 192; rel = 1; cur = cursor_a; pay = payload_a;
    } else if (gid < E1n + E2n + E3n) {
        e = gid - E1n - E2n; src = ei3; dst = ei3 + E3n; w = w3;
        stride = 192; kbase = 64; rel = 0; cur = cursor_q; pay = payload_q;
    } else {
        return;
    }
    const int s = src[e];
    const int d = dst[e];
    if ((unsigned)d >= (unsigned)NQn) return;   // guaranteed not to happen; memory safety
    const int slot = atomicAdd(&cur[d], 1);
    if (slot < SLOTS)
        pay[(size_t)d * SLOTS + slot] =
            make_int2((s * stride + kbase) | rel, __float_as_int(w[e]));
}

// -------- gather + softmax + gelu + MFMA-Wo + skip -------------------------
// Merged A-side + Q-side launch. One node per 8-lane group => 8 concurrent
// edge-chains/wave. 2-deep software pipeline — K/V for edge i+1 issued during
// compute of edge i (payload runs 2 ahead, clamped tail). <=64 VGPR tier.
struct GArgs {
    const int* cursor; const int2* payload; const u16* srcArr;
    const u16* qArr; const u16* h_in;
    const u16* Wof; const float* bo; const float* skip;
    u16* z_out;
    int qStride; int N; int ntiles; int t0; int t1;
};

__global__ __launch_bounds__(256, 8) void gather_finalize(
    GArgs A, GArgs Q, const float* __restrict__ p_rel)
{
    __shared__ __align__(16) short sG[4][16 * 72];     // per-wave gelu rows (bf16)
    __shared__ __align__(16) short sHh[4][16 * 72];    // per-wave h rows -> z rows

    const bool isA = (int)blockIdx.x < A.ntiles;
    const GArgs& G = isA ? A : Q;
    const int tile = isA ? (int)blockIdx.x : (int)blockIdx.x - A.ntiles;

    const int tid = threadIdx.x;
    const int wave = tid >> 6, lane = tid & 63;
    const int quad = lane >> 4, mrow = lane & 15;
    const int grp = lane >> 3;       // node group 0..7
    const int gl = lane & 7;         // lane within group; holds channels 8gl..8gl+7
    const int ghead = gl >> 2;       // head of this lane's channels
    const int srow = lane >> 2;      // store-phase row
    const int scol = (lane & 3) * 16;

    const float sk = sigmoidf_(G.skip[0]);
    const float isq = 0.17677669529663687f;   // 1/sqrt(32)
    const float s0 = p_rel[G.t0 * 2 + ghead] * isq;
    const float s1 = p_rel[G.t1 * 2 + ghead] * isq;

    short* const myG = &sG[wave][0];
    short* const myHh = &sHh[wave][0];

    const int N = G.N;
    const int nbase = tile * 64 + wave * 16;

    // hoisted in-degree loads for both subs (breaks cursor->payload hop)
    int cnt2[2];
    #pragma unroll
    for (int sub = 0; sub < 2; ++sub) {
        const int node = nbase + sub * 8 + grp;
        int c = (node < N && node < NQn) ? G.cursor[node] : 0;
        cnt2[sub] = (c > SLOTS) ? SLOTS : c;
    }

    #pragma unroll
    for (int sub = 0; sub < 2; ++sub) {
        const int nl = sub * 8 + grp;
        const int node = nbase + nl;
        const bool valid = node < N;
        const int cnt = cnt2[sub];
        uint4 qraw = make_uint4(0, 0, 0, 0), hraw = make_uint4(0, 0, 0, 0);
        if (valid) {
            qraw = *(const uint4*)(G.qArr + (size_t)node * G.qStride + gl * 8);
            hraw = *(const uint4*)(G.h_in + (size_t)node * 64 + gl * 8);
        }
        *(uint4*)&myHh[nl * 72 + gl * 8] = hraw;
        const float qv0 = bf2f_lo(qraw.x), qv1 = bf2f_hi(qraw.x);
        const float qv2 = bf2f_lo(qraw.y), qv3 = bf2f_hi(qraw.y);
        const float qv4 = bf2f_lo(qraw.z), qv5 = bf2f_hi(qraw.z);
        const float qv6 = bf2f_lo(qraw.w), qv7 = bf2f_hi(qraw.w);

        const int2* pp = G.payload + (size_t)node * SLOTS;
        float a0 = 0.f, a1 = 0.f, a2 = 0.f, a3 = 0.f;
        float a4 = 0.f, a5 = 0.f, a6 = 0.f, a7 = 0.f, den = 0.f;
        if (cnt > 0) {
            int2 ecur = pp[0];
            int2 enext = pp[(cnt > 1) ? 1 : 0];
            int koff = ecur.x & ~31;
            uint4 kcur = *(const uint4*)(G.srcArr + (size_t)koff + gl * 8);
            uint4 vcur = *(const uint4*)(G.srcArr + (size_t)koff + 64 + gl * 8);
            for (int i = 0; i < cnt; ++i) {
                // prefetch K/V for i+1 (clamped: tail reloads an L1-hot line)
                const int koff2 = enext.x & ~31;
                const uint4 kn = *(const uint4*)(G.srcArr + (size_t)koff2 + gl * 8);
                const uint4 vn = *(const uint4*)(G.srcArr + (size_t)koff2 + 64 + gl * 8);
                const int ip2 = (i + 2 < cnt) ? (i + 2) : (cnt - 1);
                const int2 en3 = pp[ip2];
                // compute edge i
                float p = qv0 * bf2f_lo(kcur.x) + qv1 * bf2f_hi(kcur.x)
                        + qv2 * bf2f_lo(kcur.y) + qv3 * bf2f_hi(kcur.y)
                        + qv4 * bf2f_lo(kcur.z) + qv5 * bf2f_hi(kcur.z)
                        + qv6 * bf2f_lo(kcur.w) + qv7 * bf2f_hi(kcur.w);
                p += __shfl_xor(p, 1);   // reduce over the 4 lanes of this head
                p += __shfl_xor(p, 2);
                const float sc = (ecur.x & 1) ? s1 : s0;
                const float exv = __expf(p * sc);
                const float ew = exv * __int_as_float(ecur.y);
                a0 = fmaf(ew, bf2f_lo(vcur.x), a0); a1 = fmaf(ew, bf2f_hi(vcur.x), a1);
                a2 = fmaf(ew, bf2f_lo(vcur.y), a2); a3 = fmaf(ew, bf2f_hi(vcur.y), a3);
                a4 = fmaf(ew, bf2f_lo(vcur.z), a4); a5 = fmaf(ew, bf2f_hi(vcur.z), a5);
                a6 = fmaf(ew, bf2f_lo(vcur.w), a6); a7 = fmaf(ew, bf2f_hi(vcur.w), a7);
                den += exv;
                // rotate pipeline
                ecur = enext; enext = en3; kcur = kn; vcur = vn;
            }
        }

        const float inv = 1.f / (den + 1e-16f);
        float gv[8] = {a0 * inv, a1 * inv, a2 * inv, a3 * inv,
                       a4 * inv, a5 * inv, a6 * inv, a7 * inv};
        #pragma unroll
        for (int j = 0; j < 8; ++j) {
            const float xx = gv[j];
            const float u = 0.7978845608028654f * (xx + 0.044715f * xx * xx * xx);
            const float th = 1.f - 2.f / (__expf(2.f * u) + 1.f);
            gv[j] = 0.5f * xx * (1.f + th);
        }
        uint4 gp;
        gp.x = (unsigned)f2bf(gv[0]) | ((unsigned)f2bf(gv[1]) << 16);
        gp.y = (unsigned)f2bf(gv[2]) | ((unsigned)f2bf(gv[3]) << 16);
        gp.z = (unsigned)f2bf(gv[4]) | ((unsigned)f2bf(gv[5]) << 16);
        gp.w = (unsigned)f2bf(gv[6]) | ((unsigned)f2bf(gv[7]) << 16);
        *(uint4*)&myG[nl * 72 + gl * 8] = gp;
    }

    // wave-private MFMA: Z16x64 = G16x64 @ Wo64x64 (+bo), skip blend -> myHh
    short8 ag[2];
    #pragma unroll
    for (int kt = 0; kt < 2; ++kt)
        ag[kt] = *(const short8*)&myG[mrow * 72 + kt * 32 + quad * 8];

    #pragma unroll
    for (int nt = 0; nt < 4; ++nt) {
        const float bov = G.bo[nt * 16 + mrow];
        f32x4 acc = {bov, bov, bov, bov};
        const short8 b0 = *(const short8*)&G.Wof[((0 * 4 + nt) * 64 + lane) * 8];
        acc = __builtin_amdgcn_mfma_f32_16x16x32_bf16(ag[0], b0, acc, 0, 0, 0);
        const short8 b1 = *(const short8*)&G.Wof[((1 * 4 + nt) * 64 + lane) * 8];
        acc = __builtin_amdgcn_mfma_f32_16x16x32_bf16(ag[1], b1, acc, 0, 0, 0);
        #pragma unroll
        for (int r = 0; r < 4; ++r) {
            const int row = quad * 4 + r;
            const int a = row * 72 + nt * 16 + mrow;
            const float hv = bf2f((u16)myHh[a]);
            myHh[a] = (short)f2bf(sk * acc[r] + (1.f - sk) * hv);
        }
    }

    // coalesced z store: 16 rows x 128 B = 2 KB contiguous (NT)
    if (nbase + 16 <= N) {
        const u32x4 w0 = *(const u32x4*)&myHh[srow * 72 + scol];
        const u32x4 w1 = *(const u32x4*)&myHh[srow * 72 + scol + 8];
        __builtin_nontemporal_store(w0, (u32x4*)(G.z_out + (size_t)nbase * 64 + (size_t)lane * 16));
        __builtin_nontemporal_store(w1, (u32x4*)(G.z_out + (size_t)nbase * 64 + (size_t)lane * 16 + 8));
    } else {
        for (int e2 = lane; e2 < 16 * 64; e2 += 64) {
            const int r = e2 >> 6, c = e2 & 63;
            const int nd = nbase + r;
            if (nd < N) G.z_out[(size_t)nd * 64 + c] = (u16)myHh[r * 72 + c];
        }
    }
}

// -------- decoder: sigmoid(dot64) link prediction --------------------------
__global__ __launch_bounds__(256) void decoder_kernel(
    const u16* __restrict__ z_q, const u16* __restrict__ z_a,
    const int* __restrict__ pos_idx, const int* __restrict__ neg_idx,
    float* __restrict__ out)
{
    const int gid = blockIdx.x * 256 + threadIdx.x;
    const int o = gid >> 5;         // half-wave per output
    if (o >= 2 * NLn) return;
    const int lane = threadIdx.x & 31;
    const int* idx;
    int i;
    if (o < NLn) { idx = pos_idx; i = o; }
    else         { idx = neg_idx; i = o - NLn; }
    const int r0 = idx[i];
    const int r1 = idx[NLn + i];
    const unsigned uq = *(const unsigned*)(z_q + (size_t)r0 * 64 + 2 * lane);
    const unsigned ua = *(const unsigned*)(z_a + (size_t)r1 * 64 + 2 * lane);
    float s = bf2f_lo(uq) * bf2f_lo(ua) + bf2f_hi(uq) * bf2f_hi(ua);
    s += __shfl_xor(s, 16);
    s += __shfl_xor(s, 8);
    s += __shfl_xor(s, 4);
    s += __shfl_xor(s, 2);
    s += __shfl_xor(s, 1);
    if (lane == 0) out[o] = sigmoidf_(s);
}

extern "C" void kernel_launch(void* const* d_in, const int* in_sizes, int n_in,
                              void* d_out, int out_size, void* d_ws, size_t ws_size,
                              hipStream_t stream)
{
    (void)in_sizes; (void)n_in; (void)out_size;
    const float* x_q   = (const float*)d_in[0];
    const float* x_a   = (const float*)d_in[1];
    const int* ei_qca  = (const int*)d_in[2];
    const int* ei_qwa  = (const int*)d_in[3];
    const int* ei_rev  = (const int*)d_in[4];
    const int* pos_idx = (const int*)d_in[5];
    const int* neg_idx = (const int*)d_in[6];
    const float* w_qca = (const float*)d_in[7];
    const float* w_qwa = (const float*)d_in[8];
    const float* w_rev = (const float*)d_in[9];
    const float* W_in_q = (const float*)d_in[10]; const float* b_in_q = (const float*)d_in[11];
    const float* W_in_a = (const float*)d_in[12]; const float* b_in_a = (const float*)d_in[13];
    const float* Wk_qn = (const float*)d_in[14], *bk_qn = (const float*)d_in[15];
    const float* Wq_qn = (const float*)d_in[16], *bq_qn = (const float*)d_in[17];
    const float* Wv_qn = (const float*)d_in[18], *bv_qn = (const float*)d_in[19];
    const float* Wk_an = (const float*)d_in[20], *bk_an = (const float*)d_in[21];
    const float* Wq_an = (const float*)d_in[22], *bq_an = (const float*)d_in[23];
    const float* Wv_an = (const float*)d_in[24], *bv_an = (const float*)d_in[25];
    const float* a_rel = (const float*)d_in[26];
    const float* m_rel = (const float*)d_in[27];
    const float* p_rel = (const float*)d_in[28];
    const float* Wo_qn = (const float*)d_in[29], *bo_qn = (const float*)d_in[30];
    const float* Wo_an = (const float*)d_in[31], *bo_an = (const float*)d_in[32];
    const float* skip_qn = (const float*)d_in[33], *skip_an = (const float*)d_in[34];

    char* ws = (char*)d_ws;
    size_t off = 0;
    auto alloc = [&](size_t bytes) -> char* {
        char* p = ws + off;
        off = (off + bytes + 255) & ~(size_t)255;
        return p;
    };
    u16* big_q = (u16*)alloc((size_t)NQn * 320 * 2);  // q | k0 | v0 | k1 | v1
    u16* big_a = (u16*)alloc((size_t)NAn * 192 * 2);  // q | k2 | v2
    u16* h_q   = (u16*)alloc((size_t)NQn * 64 * 2);
    u16* h_a   = (u16*)alloc((size_t)NAn * 64 * 2);
    u16* z_q   = (u16*)alloc((size_t)NQn * 64 * 2);
    u16* z_a   = (u16*)alloc((size_t)NAn * 64 * 2);
    int2* payload_a = (int2*)alloc((size_t)NQn * SLOTS * 8);  // dst of E1/E2 < NQn
    int2* payload_q = (int2*)alloc((size_t)NQn * SLOTS * 8);
    char* zero_start = ws + off;
    int* cursor_a = (int*)alloc((size_t)NQn * 4);
    int* cursor_q = (int*)alloc((size_t)NQn * 4);
    char* zero_end = ws + off;
    u16* Wbigf_q = (u16*)alloc(64 * 320 * 2);
    float* bbig_q = (float*)alloc(320 * 4);
    u16* Wbigf_a = (u16*)alloc(64 * 192 * 2);
    float* bbig_a = (float*)alloc(192 * 4);
    u16* Wof_a = (u16*)alloc(4096 * 2);
    u16* Wof_q = (u16*)alloc(4096 * 2);
    u16* Winf_q = (u16*)alloc(8192 * 2);
    u16* Winf_a = (u16*)alloc(8192 * 2);

    if (off > ws_size) return;  // workspace too small: leave output zeroed (visible failure)

    hipMemsetAsync(zero_start, 0, (size_t)(zero_end - zero_start), stream);

    fold_kernel<<<64, 256, 0, stream>>>(Wk_qn, Wv_qn, Wq_qn, bk_qn, bv_qn, bq_qn,
                                        a_rel, m_rel, 0, 1, Wbigf_q, bbig_q, 320);
    fold_kernel<<<64, 256, 0, stream>>>(Wk_an, Wv_an, Wq_an, bk_an, bv_an, bq_an,
                                        a_rel, m_rel, 2, -1, Wbigf_a, bbig_a, 192);
    fold_small<<<96, 256, 0, stream>>>(W_in_q, Winf_q, W_in_a, Winf_a,
                                       Wo_an, Wof_a, Wo_qn, Wof_q);

    node_mfma<320><<<768, 256, 0, stream>>>(x_q, NQn, Winf_q, b_in_q,
                                            Wbigf_q, bbig_q, h_q, big_q);
    node_mfma<192><<<1024, 256, 0, stream>>>(x_a, NAn, Winf_a, b_in_a,
                                             Wbigf_a, bbig_a, h_a, big_a);

    scatter_all<<<(E1n + E2n + E3n + 255) / 256, 256, 0, stream>>>(
        ei_qca, ei_qwa, ei_rev, w_qca, w_qwa, w_rev,
        cursor_a, cursor_q, payload_a, payload_q);

    // merged gather: blocks [0, ntA) = answer side, [ntA, ntA+ntQ) = question side
    const int ntA = (NAn + 63) >> 6;   // 3125
    const int ntQ = (NQn + 63) >> 6;   // 1563
    GArgs A, Q;
    A.cursor = cursor_a; A.payload = payload_a; A.srcArr = big_q;
    A.qArr = big_a; A.h_in = h_a; A.Wof = Wof_a; A.bo = bo_an; A.skip = skip_an;
    A.z_out = z_a; A.qStride = 192; A.N = NAn; A.ntiles = ntA; A.t0 = 0; A.t1 = 1;
    Q.cursor = cursor_q; Q.payload = payload_q; Q.srcArr = big_a;
    Q.qArr = big_q; Q.h_in = h_q; Q.Wof = Wof_q; Q.bo = bo_qn; Q.skip = skip_qn;
    Q.z_out = z_q; Q.qStride = 320; Q.N = NQn; Q.ntiles = ntQ; Q.t0 = 2; Q.t1 = 2;
    gather_finalize<<<ntA + ntQ, 256, 0, stream>>>(A, Q, p_rel);

    decoder_kernel<<<(2 * NLn * 32 + 255) / 256, 256, 0, stream>>>(
        z_q, z_a, pos_idx, neg_idx, (float*)d_out);
}

// Round 9
// 521.161 us; speedup vs baseline: 1.0250x; 1.0250x over previous
//
#include <hip/hip_runtime.h>

typedef unsigned short u16;
typedef __attribute__((ext_vector_type(8))) short short8;   // 8 bf16 = 4 VGPRs
typedef __attribute__((ext_vector_type(4))) float f32x4;
typedef __attribute__((ext_vector_type(4))) unsigned int u32x4;  // NT-capable uint4

#define NQn 100000
#define NAn 200000
#define E1n 250000
#define E2n 250000
#define E3n 500000
#define NLn 100000
#define SLOTS 40   // max in-degree bucket capacity; Poisson(5) => P(>40) ~ 1e-22

__device__ __forceinline__ float bf2f(u16 u) {
    return __uint_as_float(((unsigned)u) << 16);
}
__device__ __forceinline__ float bf2f_lo(unsigned u) {
    return __uint_as_float(u << 16);
}
__device__ __forceinline__ float bf2f_hi(unsigned u) {
    return __uint_as_float(u & 0xffff0000u);
}
__device__ __forceinline__ u16 f2bf(float f) {
    unsigned x = __float_as_uint(f);
    unsigned r = (x + 0x7fffu + ((x >> 16) & 1u)) >> 16;
    return (u16)r;
}
__device__ __forceinline__ float sigmoidf_(float x) {
    return 1.f / (1.f + __expf(-x));
}

// -------- fold per-relation transforms into K/V weights, OUTPUT IN MFMA ----
// -------- FRAGMENT LAYOUT ---------------------------------------------------
// Logical Wbig cols: [0,64): Wq ; [64,128): Wk@A(t0) ; [128,192): Wv@M(t0) ;
//                    [192,256): Wk@A(t1) ; [256,320): Wv@M(t1)
// Fragment layout: Wbigf[(((k>>5)*NT + (col>>4))*64 + ((k&31)>>3)*16 + (col&15))*8 + (k&7)]
__global__ void fold_kernel(
    const float* __restrict__ Wk, const float* __restrict__ Wv, const float* __restrict__ Wq,
    const float* __restrict__ bk, const float* __restrict__ bv, const float* __restrict__ bq,
    const float* __restrict__ a_rel, const float* __restrict__ m_rel,
    int t0, int t1, u16* __restrict__ Wbigf, float* __restrict__ bbig, int NOUT)
{
    const int NT = NOUT >> 4;
    const int total = 65 * NOUT;   // 64 weight rows + 1 bias row
    for (int idx = blockIdx.x * blockDim.x + threadIdx.x; idx < total;
         idx += gridDim.x * blockDim.x) {
        const int c   = idx / NOUT;
        const int col = idx - c * NOUT;
        const int grp = col >> 6;
        const int oc  = col & 63;
        const int h   = oc >> 5, e = oc & 31;
        if (c < 64) {
            float val;
            if (grp == 0) {
                val = Wq[c * 64 + oc];
            } else {
                const int t = (grp <= 2) ? t0 : t1;
                const float* W = (grp & 1) ? Wk : Wv;
                const float* T = (grp & 1) ? a_rel : m_rel;
                float s = 0.f;
                for (int d = 0; d < 32; ++d)
                    s = fmaf(W[c * 64 + h * 32 + d],
                             T[((t * 2 + h) * 32 + d) * 32 + e], s);
                val = s;
            }
            const int fi = (((c >> 5) * NT + (col >> 4)) * 64
                            + ((c & 31) >> 3) * 16 + (col & 15)) * 8 + (c & 7);
            Wbigf[fi] = f2bf(val);
        } else {
            float val;
            if (grp == 0) {
                val = bq[oc];
            } else {
                const int t = (grp <= 2) ? t0 : t1;
                const float* B = (grp & 1) ? bk : bv;
                const float* T = (grp & 1) ? a_rel : m_rel;
                float s = 0.f;
                for (int d = 0; d < 32; ++d)
                    s = fmaf(B[h * 32 + d],
                             T[((t * 2 + h) * 32 + d) * 32 + e], s);
                val = s;
            }
            bbig[col] = val;
        }
    }
}

// -------- fold [K x 64] f32 weights into MFMA fragment layout (bf16) -------
// Wf[(f*64+ln)*8+j] = W[(kt*32+(ln>>4)*8+j)*64 + nt*16+(ln&15)], f=kt*4+nt.
// Handles Win_q (K=128), Win_a (K=128), Wo_an (K=64), Wo_qn (K=64) in one launch.
__global__ void fold_small(
    const float* __restrict__ Winq, u16* __restrict__ Winfq,
    const float* __restrict__ Wina, u16* __restrict__ Winfa,
    const float* __restrict__ WoA, u16* __restrict__ WofA,
    const float* __restrict__ WoQ, u16* __restrict__ WofQ)
{
    const int gid = blockIdx.x * 256 + threadIdx.x;
    const float* W; u16* Wf; int t;
    if (gid < 8192)        { W = Winq; Wf = Winfq; t = gid; }
    else if (gid < 16384)  { W = Wina; Wf = Winfa; t = gid - 8192; }
    else if (gid < 20480)  { W = WoA;  Wf = WofA;  t = gid - 16384; }
    else if (gid < 24576)  { W = WoQ;  Wf = WofQ;  t = gid - 20480; }
    else return;
    const int j = t & 7, ln = (t >> 3) & 63, f = t >> 9;
    const int kt = f >> 2, nt = f & 3;
    const int k = kt * 32 + (ln >> 4) * 8 + j;
    const int n = nt * 16 + (ln & 15);
    Wf[t] = f2bf(W[k * 64 + n]);
}

// -------- MFMA fused node projection --------------------------------------
// r7: full-line stores. r6 post-mortem: the (srow=lane>>2, scol=(lane&3)*16)
// store pattern writes interleaved HALF-lines per instruction (4x16B with
// gaps per 128-B line); under high occupancy (+NT eager writeback) the halves
// flush separately => WRITE 2x ideal + RMW sector FETCH +80 MB. New mapping
// (row=lane>>3, col=(lane&7)*8): each instruction writes 8 whole aligned
// 128-B lines. NT kept — with full lines it is purely beneficial.
template <int NOUT>
__global__ __launch_bounds__(256, 4) void node_mfma(
    const float* __restrict__ x, int N,
    const u16* __restrict__ Winf, const float* __restrict__ bin,
    const u16* __restrict__ Wbigf, const float* __restrict__ bbig,
    u16* __restrict__ h_out, u16* __restrict__ big_out)
{
    constexpr int NT = NOUT / 16;            // stage-2 col tiles
    constexpr int NG = NT / 4;               // stage-2 64-col store groups
    __shared__ __align__(16) short sB2[2 * NT * 64 * 8];  // [kt2][nt][lane][j]
    __shared__ __align__(16) short sH[4][16 * 72];        // per-wave tile, stride 72

    const int tid = threadIdx.x;
    for (int idx = tid; idx < 2 * NT * 64; idx += 256)
        ((u32x4*)sB2)[idx] = ((const u32x4*)Wbigf)[idx];
    __syncthreads();

    const int wave = tid >> 6;
    const int lane = tid & 63;
    const int quad = lane >> 4;
    const int mrow = lane & 15;
    short* const myH = &sH[wave][0];
    const int prow = lane >> 3;              // store-phase row (8 rows/instr)
    const int pcol = (lane & 7) * 8;         // 16-B chunk within 128-B row

    // stage-1 B fragments in registers (16 x short8 = 64 VGPR), coalesced loads
    short8 wb1[16];
    #pragma unroll
    for (int f = 0; f < 16; ++f)
        wb1[f] = *(const short8*)&Winf[(f * 64 + lane) * 8];
    float bin4[4];
    #pragma unroll
    for (int nt = 0; nt < 4; ++nt) bin4[nt] = bin[nt * 16 + mrow];

    const int ntiles = (N + 63) >> 6;
    for (int tile = blockIdx.x; tile < ntiles; tile += gridDim.x) {
        const int nbase = tile * 64 + wave * 16;
        const int node = nbase + mrow;
        const bool fullgrp = (nbase + 16 <= N);

        short8 a1[4];
        if (node < N) {
            const float* xp = x + (size_t)node * 128 + quad * 8;
            #pragma unroll
            for (int kt = 0; kt < 4; ++kt) {
                const f32x4 u0 = __builtin_nontemporal_load((const f32x4*)(xp + kt * 32));
                const f32x4 u1 = __builtin_nontemporal_load((const f32x4*)(xp + kt * 32 + 4));
                short8 f;
                f[0] = (short)f2bf(u0.x); f[1] = (short)f2bf(u0.y);
                f[2] = (short)f2bf(u0.z); f[3] = (short)f2bf(u0.w);
                f[4] = (short)f2bf(u1.x); f[5] = (short)f2bf(u1.y);
                f[6] = (short)f2bf(u1.z); f[7] = (short)f2bf(u1.w);
                a1[kt] = f;
            }
        } else {
            #pragma unroll
            for (int kt = 0; kt < 4; ++kt) a1[kt] = short8{0,0,0,0,0,0,0,0};
        }

        // ---- stage 1: h = relu(x@Win + b1) -> myH ----
        #pragma unroll
        for (int nt = 0; nt < 4; ++nt) {
            const float bv = bin4[nt];
            f32x4 acc = {bv, bv, bv, bv};
            #pragma unroll
            for (int kt = 0; kt < 4; ++kt)
                acc = __builtin_amdgcn_mfma_f32_16x16x32_bf16(a1[kt], wb1[kt * 4 + nt],
                                                              acc, 0, 0, 0);
            #pragma unroll
            for (int r = 0; r < 4; ++r)
                myH[(quad * 4 + r) * 72 + nt * 16 + mrow] =
                    (short)f2bf(fmaxf(acc[r], 0.f));
        }

        // ---- h store: 2 instrs x 8 whole 128-B lines (full-line, NT) ----
        if (fullgrp) {
            const u32x4 w0 = *(const u32x4*)&myH[prow * 72 + pcol];
            const u32x4 w1 = *(const u32x4*)&myH[(prow + 8) * 72 + pcol];
            __builtin_nontemporal_store(w0, (u32x4*)(h_out + (size_t)(nbase + prow) * 64 + pcol));
            __builtin_nontemporal_store(w1, (u32x4*)(h_out + (size_t)(nbase + prow + 8) * 64 + pcol));
        } else {
            for (int e = lane; e < 16 * 64; e += 64) {
                const int r = e >> 6, c = e & 63;
                const int nd = nbase + r;
                if (nd < N) h_out[(size_t)nd * 64 + c] = (u16)myH[r * 72 + c];
            }
        }

        // ---- stage 2: big = h @ Wbig + b2, grouped 64-col staging ----
        short8 a2[2];
        #pragma unroll
        for (int kt2 = 0; kt2 < 2; ++kt2)
            a2[kt2] = *(const short8*)&myH[mrow * 72 + kt2 * 32 + quad * 8];

        #pragma unroll
        for (int g = 0; g < NG; ++g) {
            #pragma unroll
            for (int q2 = 0; q2 < 4; ++q2) {
                const int nt = g * 4 + q2;
                const float bv = bbig[nt * 16 + mrow];
                f32x4 acc = {bv, bv, bv, bv};
                const short8 b0 = *(const short8*)&sB2[((0 * NT + nt) * 64 + lane) * 8];
                acc = __builtin_amdgcn_mfma_f32_16x16x32_bf16(a2[0], b0, acc, 0, 0, 0);
                const short8 b1 = *(const short8*)&sB2[((1 * NT + nt) * 64 + lane) * 8];
                acc = __builtin_amdgcn_mfma_f32_16x16x32_bf16(a2[1], b1, acc, 0, 0, 0);
                #pragma unroll
                for (int r = 0; r < 4; ++r)
                    myH[(quad * 4 + r) * 72 + q2 * 16 + mrow] = (short)f2bf(acc[r]);
            }
            // ---- big store: 2 instrs x 8 whole 128-B segments (full-line, NT) ----
            // (NOUT*2 bytes = 384/640 B row stride, both multiples of 128 B)
            if (fullgrp) {
                const u32x4 w0 = *(const u32x4*)&myH[prow * 72 + pcol];
                const u32x4 w1 = *(const u32x4*)&myH[(prow + 8) * 72 + pcol];
                __builtin_nontemporal_store(w0,
                    (u32x4*)(big_out + (size_t)(nbase + prow) * NOUT + g * 64 + pcol));
                __builtin_nontemporal_store(w1,
                    (u32x4*)(big_out + (size_t)(nbase + prow + 8) * NOUT + g * 64 + pcol));
            } else {
                for (int e = lane; e < 16 * 64; e += 64) {
                    const int r = e >> 6, c = e & 63;
                    const int nd = nbase + r;
                    if (nd < N)
                        big_out[(size_t)nd * NOUT + g * 64 + c] = (u16)myH[r * 72 + c];
                }
            }
        }
    }
}

// -------- merged scatter: bucket all 3 relations in one launch -------------
// payload.x = (src*srcStride + kBase) | relBit   (k-offset, mult of 32; v = +64)
// payload.y = bits of per-edge weight w
__global__ __launch_bounds__(256) void scatter_all(
    const int* __restrict__ ei1, const int* __restrict__ ei2, const int* __restrict__ ei3,
    const float* __restrict__ w1, const float* __restrict__ w2, const float* __restrict__ w3,
    int* __restrict__ cursor_a, int* __restrict__ cursor_q,
    int2* __restrict__ payload_a, int2* __restrict__ payload_q)
{
    const int gid = blockIdx.x * 256 + threadIdx.x;
    const int* src; const int* dst; const float* w;
    int e, stride, kbase, rel; int* cur; int2* pay;
    if (gid < E1n) {
        e = gid; src = ei1; dst = ei1 + E1n; w = w1;
        stride = 320; kbase = 64; rel = 0; cur = cursor_a; pay = payload_a;
    } else if (gid < E1n + E2n) {
        e = gid - E1n; src = ei2; dst = ei2 + E2n; w = w2;
        stride = 320; kbase = 192; rel = 1; cur = cursor_a; pay = payload_a;
    } else if (gid < E1n + E2n + E3n) {
        e = gid - E1n - E2n; src = ei3; dst = ei3 + E3n; w = w3;
        stride = 192; kbase = 64; rel = 0; cur = cursor_q; pay = payload_q;
    } else {
        return;
    }
    const int s = src[e];
    const int d = dst[e];
    if ((unsigned)d >= (unsigned)NQn) return;   // guaranteed not to happen; memory safety
    const int slot = atomicAdd(&cur[d], 1);
    if (slot < SLOTS)
        pay[(size_t)d * SLOTS + slot] =
            make_int2((s * stride + kbase) | rel, __float_as_int(w[e]));
}

// -------- gather + softmax + gelu + MFMA-Wo + skip -------------------------
// Merged A-side + Q-side launch. One node per 8-lane group => 8 concurrent
// edge-chains/wave. 2-deep software pipeline — K/V for edge i+1 issued during
// compute of edge i (payload runs 2 ahead, clamped tail). <=64 VGPR tier.
struct GArgs {
    const int* cursor; const int2* payload; const u16* srcArr;
    const u16* qArr; const u16* h_in;
    const u16* Wof; const float* bo; const float* skip;
    u16* z_out;
    int qStride; int N; int ntiles; int t0; int t1;
};

__global__ __launch_bounds__(256, 8) void gather_finalize(
    GArgs A, GArgs Q, const float* __restrict__ p_rel)
{
    __shared__ __align__(16) short sG[4][16 * 72];     // per-wave gelu rows (bf16)
    __shared__ __align__(16) short sHh[4][16 * 72];    // per-wave h rows -> z rows

    const bool isA = (int)blockIdx.x < A.ntiles;
    const GArgs& G = isA ? A : Q;
    const int tile = isA ? (int)blockIdx.x : (int)blockIdx.x - A.ntiles;

    const int tid = threadIdx.x;
    const int wave = tid >> 6, lane = tid & 63;
    const int quad = lane >> 4, mrow = lane & 15;
    const int grp = lane >> 3;       // node group 0..7
    const int gl = lane & 7;         // lane within group; holds channels 8gl..8gl+7
    const int ghead = gl >> 2;       // head of this lane's channels
    const int prow = lane >> 3;      // store-phase row (8 rows/instr)
    const int pcol = (lane & 7) * 8; // 16-B chunk within 128-B row

    const float sk = sigmoidf_(G.skip[0]);
    const float isq = 0.17677669529663687f;   // 1/sqrt(32)
    const float s0 = p_rel[G.t0 * 2 + ghead] * isq;
    const float s1 = p_rel[G.t1 * 2 + ghead] * isq;

    short* const myG = &sG[wave][0];
    short* const myHh = &sHh[wave][0];

    const int N = G.N;
    const int nbase = tile * 64 + wave * 16;

    // hoisted in-degree loads for both subs (breaks cursor->payload hop)
    int cnt2[2];
    #pragma unroll
    for (int sub = 0; sub < 2; ++sub) {
        const int node = nbase + sub * 8 + grp;
        int c = (node < N && node < NQn) ? G.cursor[node] : 0;
        cnt2[sub] = (c > SLOTS) ? SLOTS : c;
    }

    #pragma unroll
    for (int sub = 0; sub < 2; ++sub) {
        const int nl = sub * 8 + grp;
        const int node = nbase + nl;
        const bool valid = node < N;
        const int cnt = cnt2[sub];
        uint4 qraw = make_uint4(0, 0, 0, 0), hraw = make_uint4(0, 0, 0, 0);
        if (valid) {
            qraw = *(const uint4*)(G.qArr + (size_t)node * G.qStride + gl * 8);
            hraw = *(const uint4*)(G.h_in + (size_t)node * 64 + gl * 8);
        }
        *(uint4*)&myHh[nl * 72 + gl * 8] = hraw;
        const float qv0 = bf2f_lo(qraw.x), qv1 = bf2f_hi(qraw.x);
        const float qv2 = bf2f_lo(qraw.y), qv3 = bf2f_hi(qraw.y);
        const float qv4 = bf2f_lo(qraw.z), qv5 = bf2f_hi(qraw.z);
        const float qv6 = bf2f_lo(qraw.w), qv7 = bf2f_hi(qraw.w);

        const int2* pp = G.payload + (size_t)node * SLOTS;
        float a0 = 0.f, a1 = 0.f, a2 = 0.f, a3 = 0.f;
        float a4 = 0.f, a5 = 0.f, a6 = 0.f, a7 = 0.f, den = 0.f;
        if (cnt > 0) {
            int2 ecur = pp[0];
            int2 enext = pp[(cnt > 1) ? 1 : 0];
            int koff = ecur.x & ~31;
            uint4 kcur = *(const uint4*)(G.srcArr + (size_t)koff + gl * 8);
            uint4 vcur = *(const uint4*)(G.srcArr + (size_t)koff + 64 + gl * 8);
            for (int i = 0; i < cnt; ++i) {
                // prefetch K/V for i+1 (clamped: tail reloads an L1-hot line)
                const int koff2 = enext.x & ~31;
                const uint4 kn = *(const uint4*)(G.srcArr + (size_t)koff2 + gl * 8);
                const uint4 vn = *(const uint4*)(G.srcArr + (size_t)koff2 + 64 + gl * 8);
                const int ip2 = (i + 2 < cnt) ? (i + 2) : (cnt - 1);
                const int2 en3 = pp[ip2];
                // compute edge i
                float p = qv0 * bf2f_lo(kcur.x) + qv1 * bf2f_hi(kcur.x)
                        + qv2 * bf2f_lo(kcur.y) + qv3 * bf2f_hi(kcur.y)
                        + qv4 * bf2f_lo(kcur.z) + qv5 * bf2f_hi(kcur.z)
                        + qv6 * bf2f_lo(kcur.w) + qv7 * bf2f_hi(kcur.w);
                p += __shfl_xor(p, 1);   // reduce over the 4 lanes of this head
                p += __shfl_xor(p, 2);
                const float sc = (ecur.x & 1) ? s1 : s0;
                const float exv = __expf(p * sc);
                const float ew = exv * __int_as_float(ecur.y);
                a0 = fmaf(ew, bf2f_lo(vcur.x), a0); a1 = fmaf(ew, bf2f_hi(vcur.x), a1);
                a2 = fmaf(ew, bf2f_lo(vcur.y), a2); a3 = fmaf(ew, bf2f_hi(vcur.y), a3);
                a4 = fmaf(ew, bf2f_lo(vcur.z), a4); a5 = fmaf(ew, bf2f_hi(vcur.z), a5);
                a6 = fmaf(ew, bf2f_lo(vcur.w), a6); a7 = fmaf(ew, bf2f_hi(vcur.w), a7);
                den += exv;
                // rotate pipeline
                ecur = enext; enext = en3; kcur = kn; vcur = vn;
            }
        }

        const float inv = 1.f / (den + 1e-16f);
        float gv[8] = {a0 * inv, a1 * inv, a2 * inv, a3 * inv,
                       a4 * inv, a5 * inv, a6 * inv, a7 * inv};
        #pragma unroll
        for (int j = 0; j < 8; ++j) {
            const float xx = gv[j];
            const float u = 0.7978845608028654f * (xx + 0.044715f * xx * xx * xx);
            const float th = 1.f - 2.f / (__expf(2.f * u) + 1.f);
            gv[j] = 0.5f * xx * (1.f + th);
        }
        uint4 gp;
        gp.x = (unsigned)f2bf(gv[0]) | ((unsigned)f2bf(gv[1]) << 16);
        gp.y = (unsigned)f2bf(gv[2]) | ((unsigned)f2bf(gv[3]) << 16);
        gp.z = (unsigned)f2bf(gv[4]) | ((unsigned)f2bf(gv[5]) << 16);
        gp.w = (unsigned)f2bf(gv[6]) | ((unsigned)f2bf(gv[7]) << 16);
        *(uint4*)&myG[nl * 72 + gl * 8] = gp;
    }

    // wave-private MFMA: Z16x64 = G16x64 @ Wo64x64 (+bo), skip blend -> myHh
    short8 ag[2];
    #pragma unroll
    for (int kt = 0; kt < 2; ++kt)
        ag[kt] = *(const short8*)&myG[mrow * 72 + kt * 32 + quad * 8];

    #pragma unroll
    for (int nt = 0; nt < 4; ++nt) {
        const float bov = G.bo[nt * 16 + mrow];
        f32x4 acc = {bov, bov, bov, bov};
        const short8 b0 = *(const short8*)&G.Wof[((0 * 4 + nt) * 64 + lane) * 8];
        acc = __builtin_amdgcn_mfma_f32_16x16x32_bf16(ag[0], b0, acc, 0, 0, 0);
        const short8 b1 = *(const short8*)&G.Wof[((1 * 4 + nt) * 64 + lane) * 8];
        acc = __builtin_amdgcn_mfma_f32_16x16x32_bf16(ag[1], b1, acc, 0, 0, 0);
        #pragma unroll
        for (int r = 0; r < 4; ++r) {
            const int row = quad * 4 + r;
            const int a = row * 72 + nt * 16 + mrow;
            const float hv = bf2f((u16)myHh[a]);
            myHh[a] = (short)f2bf(sk * acc[r] + (1.f - sk) * hv);
        }
    }

    // ---- z store: 2 instrs x 8 whole 128-B lines (full-line, NT) ----
    if (nbase + 16 <= N) {
        const u32x4 w0 = *(const u32x4*)&myHh[prow * 72 + pcol];
        const u32x4 w1 = *(const u32x4*)&myHh[(prow + 8) * 72 + pcol];
        __builtin_nontemporal_store(w0, (u32x4*)(G.z_out + (size_t)(nbase + prow) * 64 + pcol));
        __builtin_nontemporal_store(w1, (u32x4*)(G.z_out + (size_t)(nbase + prow + 8) * 64 + pcol));
    } else {
        for (int e2 = lane; e2 < 16 * 64; e2 += 64) {
            const int r = e2 >> 6, c = e2 & 63;
            const int nd = nbase + r;
            if (nd < N) G.z_out[(size_t)nd * 64 + c] = (u16)myHh[r * 72 + c];
        }
    }
}

// -------- decoder: sigmoid(dot64) link prediction --------------------------
__global__ __launch_bounds__(256) void decoder_kernel(
    const u16* __restrict__ z_q, const u16* __restrict__ z_a,
    const int* __restrict__ pos_idx, const int* __restrict__ neg_idx,
    float* __restrict__ out)
{
    const int gid = blockIdx.x * 256 + threadIdx.x;
    const int o = gid >> 5;         // half-wave per output
    if (o >= 2 * NLn) return;
    const int lane = threadIdx.x & 31;
    const int* idx;
    int i;
    if (o < NLn) { idx = pos_idx; i = o; }
    else         { idx = neg_idx; i = o - NLn; }
    const int r0 = idx[i];
    const int r1 = idx[NLn + i];
    const unsigned uq = *(const unsigned*)(z_q + (size_t)r0 * 64 + 2 * lane);
    const unsigned ua = *(const unsigned*)(z_a + (size_t)r1 * 64 + 2 * lane);
    float s = bf2f_lo(uq) * bf2f_lo(ua) + bf2f_hi(uq) * bf2f_hi(ua);
    s += __shfl_xor(s, 16);
    s += __shfl_xor(s, 8);
    s += __shfl_xor(s, 4);
    s += __shfl_xor(s, 2);
    s += __shfl_xor(s, 1);
    if (lane == 0) out[o] = sigmoidf_(s);
}

extern "C" void kernel_launch(void* const* d_in, const int* in_sizes, int n_in,
                              void* d_out, int out_size, void* d_ws, size_t ws_size,
                              hipStream_t stream)
{
    (void)in_sizes; (void)n_in; (void)out_size;
    const float* x_q   = (const float*)d_in[0];
    const float* x_a   = (const float*)d_in[1];
    const int* ei_qca  = (const int*)d_in[2];
    const int* ei_qwa  = (const int*)d_in[3];
    const int* ei_rev  = (const int*)d_in[4];
    const int* pos_idx = (const int*)d_in[5];
    const int* neg_idx = (const int*)d_in[6];
    const float* w_qca = (const float*)d_in[7];
    const float* w_qwa = (const float*)d_in[8];
    const float* w_rev = (const float*)d_in[9];
    const float* W_in_q = (const float*)d_in[10]; const float* b_in_q = (const float*)d_in[11];
    const float* W_in_a = (const float*)d_in[12]; const float* b_in_a = (const float*)d_in[13];
    const float* Wk_qn = (const float*)d_in[14], *bk_qn = (const float*)d_in[15];
    const float* Wq_qn = (const float*)d_in[16], *bq_qn = (const float*)d_in[17];
    const float* Wv_qn = (const float*)d_in[18], *bv_qn = (const float*)d_in[19];
    const float* Wk_an = (const float*)d_in[20], *bk_an = (const float*)d_in[21];
    const float* Wq_an = (const float*)d_in[22], *bq_an = (const float*)d_in[23];
    const float* Wv_an = (const float*)d_in[24], *bv_an = (const float*)d_in[25];
    const float* a_rel = (const float*)d_in[26];
    const float* m_rel = (const float*)d_in[27];
    const float* p_rel = (const float*)d_in[28];
    const float* Wo_qn = (const float*)d_in[29], *bo_qn = (const float*)d_in[30];
    const float* Wo_an = (const float*)d_in[31], *bo_an = (const float*)d_in[32];
    const float* skip_qn = (const float*)d_in[33], *skip_an = (const float*)d_in[34];

    char* ws = (char*)d_ws;
    size_t off = 0;
    auto alloc = [&](size_t bytes) -> char* {
        char* p = ws + off;
        off = (off + bytes + 255) & ~(size_t)255;
        return p;
    };
    u16* big_q = (u16*)alloc((size_t)NQn * 320 * 2);  // q | k0 | v0 | k1 | v1
    u16* big_a = (u16*)alloc((size_t)NAn * 192 * 2);  // q | k2 | v2
    u16* h_q   = (u16*)alloc((size_t)NQn * 64 * 2);
    u16* h_a   = (u16*)alloc((size_t)NAn * 64 * 2);
    u16* z_q   = (u16*)alloc((size_t)NQn * 64 * 2);
    u16* z_a   = (u16*)alloc((size_t)NAn * 64 * 2);
    int2* payload_a = (int2*)alloc((size_t)NQn * SLOTS * 8);  // dst of E1/E2 < NQn
    int2* payload_q = (int2*)alloc((size_t)NQn * SLOTS * 8);
    char* zero_start = ws + off;
    int* cursor_a = (int*)alloc((size_t)NQn * 4);
    int* cursor_q = (int*)alloc((size_t)NQn * 4);
    char* zero_end = ws + off;
    u16* Wbigf_q = (u16*)alloc(64 * 320 * 2);
    float* bbig_q = (float*)alloc(320 * 4);
    u16* Wbigf_a = (u16*)alloc(64 * 192 * 2);
    float* bbig_a = (float*)alloc(192 * 4);
    u16* Wof_a = (u16*)alloc(4096 * 2);
    u16* Wof_q = (u16*)alloc(4096 * 2);
    u16* Winf_q = (u16*)alloc(8192 * 2);
    u16* Winf_a = (u16*)alloc(8192 * 2);

    if (off > ws_size) return;  // workspace too small: leave output zeroed (visible failure)

    hipMemsetAsync(zero_start, 0, (size_t)(zero_end - zero_start), stream);

    fold_kernel<<<64, 256, 0, stream>>>(Wk_qn, Wv_qn, Wq_qn, bk_qn, bv_qn, bq_qn,
                                        a_rel, m_rel, 0, 1, Wbigf_q, bbig_q, 320);
    fold_kernel<<<64, 256, 0, stream>>>(Wk_an, Wv_an, Wq_an, bk_an, bv_an, bq_an,
                                        a_rel, m_rel, 2, -1, Wbigf_a, bbig_a, 192);
    fold_small<<<96, 256, 0, stream>>>(W_in_q, Winf_q, W_in_a, Winf_a,
                                       Wo_an, Wof_a, Wo_qn, Wof_q);

    node_mfma<320><<<768, 256, 0, stream>>>(x_q, NQn, Winf_q, b_in_q,
                                            Wbigf_q, bbig_q, h_q, big_q);
    node_mfma<192><<<1024, 256, 0, stream>>>(x_a, NAn, Winf_a, b_in_a,
                                             Wbigf_a, bbig_a, h_a, big_a);

    scatter_all<<<(E1n + E2n + E3n + 255) / 256, 256, 0, stream>>>(
        ei_qca, ei_qwa, ei_rev, w_qca, w_qwa, w_rev,
        cursor_a, cursor_q, payload_a, payload_q);

    // merged gather: blocks [0, ntA) = answer side, [ntA, ntA+ntQ) = question side
    const int ntA = (NAn + 63) >> 6;   // 3125
    const int ntQ = (NQn + 63) >> 6;   // 1563
    GArgs A, Q;
    A.cursor = cursor_a; A.payload = payload_a; A.srcArr = big_q;
    A.qArr = big_a; A.h_in = h_a; A.Wof = Wof_a; A.bo = bo_an; A.skip = skip_an;
    A.z_out = z_a; A.qStride = 192; A.N = NAn; A.ntiles = ntA; A.t0 = 0; A.t1 = 1;
    Q.cursor = cursor_q; Q.payload = payload_q; Q.srcArr = big_a;
    Q.qArr = big_q; Q.h_in = h_q; Q.Wof = Wof_q; Q.bo = bo_qn; Q.skip = skip_qn;
    Q.z_out = z_q; Q.qStride = 320; Q.N = NQn; Q.ntiles = ntQ; Q.t0 = 2; Q.t1 = 2;
    gather_finalize<<<ntA + ntQ, 256, 0, stream>>>(A, Q, p_rel);

    decoder_kernel<<<(2 * NLn * 32 + 255) / 256, 256, 0, stream>>>(
        z_q, z_a, pos_idx, neg_idx, (float*)d_out);
}

// Round 10
// 520.589 us; speedup vs baseline: 1.0261x; 1.0011x over previous
//
#include <hip/hip_runtime.h>

typedef unsigned short u16;
typedef __attribute__((ext_vector_type(8))) short short8;   // 8 bf16 = 4 VGPRs
typedef __attribute__((ext_vector_type(4))) float f32x4;
typedef __attribute__((ext_vector_type(4))) unsigned int u32x4;  // NT-capable uint4

#define NQn 100000
#define NAn 200000
#define E1n 250000
#define E2n 250000
#define E3n 500000
#define NLn 100000
#define SLOTS 40   // max in-degree bucket capacity; Poisson(5) => P(>40) ~ 1e-22

__device__ __forceinline__ float bf2f(u16 u) {
    return __uint_as_float(((unsigned)u) << 16);
}
__device__ __forceinline__ float bf2f_lo(unsigned u) {
    return __uint_as_float(u << 16);
}
__device__ __forceinline__ float bf2f_hi(unsigned u) {
    return __uint_as_float(u & 0xffff0000u);
}
__device__ __forceinline__ u16 f2bf(float f) {
    unsigned x = __float_as_uint(f);
    unsigned r = (x + 0x7fffu + ((x >> 16) & 1u)) >> 16;
    return (u16)r;
}
__device__ __forceinline__ float sigmoidf_(float x) {
    return 1.f / (1.f + __expf(-x));
}

// -------- fold per-relation transforms into K/V weights, OUTPUT IN MFMA ----
// -------- FRAGMENT LAYOUT ---------------------------------------------------
// Logical Wbig cols: [0,64): Wq ; [64,128): Wk@A(t0) ; [128,192): Wv@M(t0) ;
//                    [192,256): Wk@A(t1) ; [256,320): Wv@M(t1)
// Fragment layout: Wbigf[(((k>>5)*NT + (col>>4))*64 + ((k&31)>>3)*16 + (col&15))*8 + (k&7)]
__global__ void fold_kernel(
    const float* __restrict__ Wk, const float* __restrict__ Wv, const float* __restrict__ Wq,
    const float* __restrict__ bk, const float* __restrict__ bv, const float* __restrict__ bq,
    const float* __restrict__ a_rel, const float* __restrict__ m_rel,
    int t0, int t1, u16* __restrict__ Wbigf, float* __restrict__ bbig, int NOUT)
{
    const int NT = NOUT >> 4;
    const int total = 65 * NOUT;   // 64 weight rows + 1 bias row
    for (int idx = blockIdx.x * blockDim.x + threadIdx.x; idx < total;
         idx += gridDim.x * blockDim.x) {
        const int c   = idx / NOUT;
        const int col = idx - c * NOUT;
        const int grp = col >> 6;
        const int oc  = col & 63;
        const int h   = oc >> 5, e = oc & 31;
        if (c < 64) {
            float val;
            if (grp == 0) {
                val = Wq[c * 64 + oc];
            } else {
                const int t = (grp <= 2) ? t0 : t1;
                const float* W = (grp & 1) ? Wk : Wv;
                const float* T = (grp & 1) ? a_rel : m_rel;
                float s = 0.f;
                for (int d = 0; d < 32; ++d)
                    s = fmaf(W[c * 64 + h * 32 + d],
                             T[((t * 2 + h) * 32 + d) * 32 + e], s);
                val = s;
            }
            const int fi = (((c >> 5) * NT + (col >> 4)) * 64
                            + ((c & 31) >> 3) * 16 + (col & 15)) * 8 + (c & 7);
            Wbigf[fi] = f2bf(val);
        } else {
            float val;
            if (grp == 0) {
                val = bq[oc];
            } else {
                const int t = (grp <= 2) ? t0 : t1;
                const float* B = (grp & 1) ? bk : bv;
                const float* T = (grp & 1) ? a_rel : m_rel;
                float s = 0.f;
                for (int d = 0; d < 32; ++d)
                    s = fmaf(B[h * 32 + d],
                             T[((t * 2 + h) * 32 + d) * 32 + e], s);
                val = s;
            }
            bbig[col] = val;
        }
    }
}

// -------- fold [K x 64] f32 weights into MFMA fragment layout (bf16) -------
// Wf[(f*64+ln)*8+j] = W[(kt*32+(ln>>4)*8+j)*64 + nt*16+(ln&15)], f=kt*4+nt.
// Handles Win_q (K=128), Win_a (K=128), Wo_an (K=64), Wo_qn (K=64) in one launch.
__global__ void fold_small(
    const float* __restrict__ Winq, u16* __restrict__ Winfq,
    const float* __restrict__ Wina, u16* __restrict__ Winfa,
    const float* __restrict__ WoA, u16* __restrict__ WofA,
    const float* __restrict__ WoQ, u16* __restrict__ WofQ)
{
    const int gid = blockIdx.x * 256 + threadIdx.x;
    const float* W; u16* Wf; int t;
    if (gid < 8192)        { W = Winq; Wf = Winfq; t = gid; }
    else if (gid < 16384)  { W = Wina; Wf = Winfa; t = gid - 8192; }
    else if (gid < 20480)  { W = WoA;  Wf = WofA;  t = gid - 16384; }
    else if (gid < 24576)  { W = WoQ;  Wf = WofQ;  t = gid - 20480; }
    else return;
    const int j = t & 7, ln = (t >> 3) & 63, f = t >> 9;
    const int kt = f >> 2, nt = f & 3;
    const int k = kt * 32 + (ln >> 4) * 8 + j;
    const int n = nt * 16 + (ln & 15);
    Wf[t] = f2bf(W[k * 64 + n]);
}

// -------- MFMA fused node projection --------------------------------------
// r10: temporal write clustering. r9 post-mortem: FETCH/WRITE inflation (~big
// size each) is invariant to store instruction shape — it is the TEMPORAL
// separation of a row's g-group chunks (128 B each, separated by MFMA bursts)
// that lets the dirty line be evicted between partial writes under streaming
// pressure => partial writeback + RMW refetch. Fix: park each g-group's store
// slice in registers, then emit all stores back-to-back so each row's full
// 384/640-B extent is written in consecutive instructions. Plain stores (no
// NT): h/big/z are consumed by gather — keep them L3-resident. NT only on x.
template <int NOUT>
__global__ __launch_bounds__(256, 4) void node_mfma(
    const float* __restrict__ x, int N,
    const u16* __restrict__ Winf, const float* __restrict__ bin,
    const u16* __restrict__ Wbigf, const float* __restrict__ bbig,
    u16* __restrict__ h_out, u16* __restrict__ big_out)
{
    constexpr int NT = NOUT / 16;            // stage-2 col tiles
    constexpr int NG = NT / 4;               // stage-2 64-col store groups
    __shared__ __align__(16) short sB2[2 * NT * 64 * 8];  // [kt2][nt][lane][j]
    __shared__ __align__(16) short sH[4][16 * 72];        // per-wave tile, stride 72

    const int tid = threadIdx.x;
    for (int idx = tid; idx < 2 * NT * 64; idx += 256)
        ((u32x4*)sB2)[idx] = ((const u32x4*)Wbigf)[idx];
    __syncthreads();

    const int wave = tid >> 6;
    const int lane = tid & 63;
    const int quad = lane >> 4;
    const int mrow = lane & 15;
    short* const myH = &sH[wave][0];
    const int prow = lane >> 3;              // store-phase row (8 rows/instr)
    const int pcol = (lane & 7) * 8;         // 16-B chunk within 128-B row

    // stage-1 B fragments in registers (16 x short8 = 64 VGPR), coalesced loads
    short8 wb1[16];
    #pragma unroll
    for (int f = 0; f < 16; ++f)
        wb1[f] = *(const short8*)&Winf[(f * 64 + lane) * 8];
    float bin4[4];
    #pragma unroll
    for (int nt = 0; nt < 4; ++nt) bin4[nt] = bin[nt * 16 + mrow];

    const int ntiles = (N + 63) >> 6;
    for (int tile = blockIdx.x; tile < ntiles; tile += gridDim.x) {
        const int nbase = tile * 64 + wave * 16;
        const int node = nbase + mrow;
        const bool fullgrp = (nbase + 16 <= N);

        short8 a1[4];
        if (node < N) {
            const float* xp = x + (size_t)node * 128 + quad * 8;
            #pragma unroll
            for (int kt = 0; kt < 4; ++kt) {
                const f32x4 u0 = __builtin_nontemporal_load((const f32x4*)(xp + kt * 32));
                const f32x4 u1 = __builtin_nontemporal_load((const f32x4*)(xp + kt * 32 + 4));
                short8 f;
                f[0] = (short)f2bf(u0.x); f[1] = (short)f2bf(u0.y);
                f[2] = (short)f2bf(u0.z); f[3] = (short)f2bf(u0.w);
                f[4] = (short)f2bf(u1.x); f[5] = (short)f2bf(u1.y);
                f[6] = (short)f2bf(u1.z); f[7] = (short)f2bf(u1.w);
                a1[kt] = f;
            }
        } else {
            #pragma unroll
            for (int kt = 0; kt < 4; ++kt) a1[kt] = short8{0,0,0,0,0,0,0,0};
        }

        // ---- stage 1: h = relu(x@Win + b1) -> myH ----
        #pragma unroll
        for (int nt = 0; nt < 4; ++nt) {
            const float bv = bin4[nt];
            f32x4 acc = {bv, bv, bv, bv};
            #pragma unroll
            for (int kt = 0; kt < 4; ++kt)
                acc = __builtin_amdgcn_mfma_f32_16x16x32_bf16(a1[kt], wb1[kt * 4 + nt],
                                                              acc, 0, 0, 0);
            #pragma unroll
            for (int r = 0; r < 4; ++r)
                myH[(quad * 4 + r) * 72 + nt * 16 + mrow] =
                    (short)f2bf(fmaxf(acc[r], 0.f));
        }

        // ---- h store: 2 back-to-back instrs, 2 KB contiguous ----
        if (fullgrp) {
            const u32x4 w0 = *(const u32x4*)&myH[prow * 72 + pcol];
            const u32x4 w1 = *(const u32x4*)&myH[(prow + 8) * 72 + pcol];
            *(u32x4*)(h_out + (size_t)(nbase + prow) * 64 + pcol) = w0;
            *(u32x4*)(h_out + (size_t)(nbase + prow + 8) * 64 + pcol) = w1;
        } else {
            for (int e = lane; e < 16 * 64; e += 64) {
                const int r = e >> 6, c = e & 63;
                const int nd = nbase + r;
                if (nd < N) h_out[(size_t)nd * 64 + c] = (u16)myH[r * 72 + c];
            }
        }

        // ---- stage 2: big = h @ Wbig + b2; park store slices in regs ----
        short8 a2[2];
        #pragma unroll
        for (int kt2 = 0; kt2 < 2; ++kt2)
            a2[kt2] = *(const short8*)&myH[mrow * 72 + kt2 * 32 + quad * 8];

        u32x4 sv0[NG], sv1[NG];
        #pragma unroll
        for (int g = 0; g < NG; ++g) {
            #pragma unroll
            for (int q2 = 0; q2 < 4; ++q2) {
                const int nt = g * 4 + q2;
                const float bv = bbig[nt * 16 + mrow];
                f32x4 acc = {bv, bv, bv, bv};
                const short8 b0 = *(const short8*)&sB2[((0 * NT + nt) * 64 + lane) * 8];
                acc = __builtin_amdgcn_mfma_f32_16x16x32_bf16(a2[0], b0, acc, 0, 0, 0);
                const short8 b1 = *(const short8*)&sB2[((1 * NT + nt) * 64 + lane) * 8];
                acc = __builtin_amdgcn_mfma_f32_16x16x32_bf16(a2[1], b1, acc, 0, 0, 0);
                #pragma unroll
                for (int r = 0; r < 4; ++r)
                    myH[(quad * 4 + r) * 72 + q2 * 16 + mrow] = (short)f2bf(acc[r]);
            }
            sv0[g] = *(const u32x4*)&myH[prow * 72 + pcol];
            sv1[g] = *(const u32x4*)&myH[(prow + 8) * 72 + pcol];
        }
        // ---- clustered big store: each row's full extent in consecutive
        // ---- instructions (rows prow: NG chunks back-to-back; then prow+8)
        if (fullgrp) {
            u16* const rb0 = big_out + (size_t)(nbase + prow) * NOUT + pcol;
            #pragma unroll
            for (int g = 0; g < NG; ++g)
                *(u32x4*)(rb0 + g * 64) = sv0[g];
            u16* const rb1 = big_out + (size_t)(nbase + prow + 8) * NOUT + pcol;
            #pragma unroll
            for (int g = 0; g < NG; ++g)
                *(u32x4*)(rb1 + g * 64) = sv1[g];
        } else {
            for (int e = lane; e < 16 * 64; e += 64) {
                const int r = e >> 6, c = e & 63;
                const int nd = nbase + r;
                if (nd < N) {
                    // myH holds only the last g-group; recompute via slices
                }
            }
            // tail: write from parked registers (each lane owns rows prow,
            // prow+8 at cols [g*64+pcol, +8) )
            #pragma unroll
            for (int g = 0; g < NG; ++g) {
                const int nd0 = nbase + prow;
                if (nd0 < N) {
                    u16* p = big_out + (size_t)nd0 * NOUT + g * 64 + pcol;
                    *(u32x4*)p = sv0[g];
                }
                const int nd1 = nbase + prow + 8;
                if (nd1 < N) {
                    u16* p = big_out + (size_t)nd1 * NOUT + g * 64 + pcol;
                    *(u32x4*)p = sv1[g];
                }
            }
        }
    }
}

// -------- merged scatter: bucket all 3 relations in one launch -------------
// payload.x = (src*srcStride + kBase) | relBit   (k-offset, mult of 32; v = +64)
// payload.y = bits of per-edge weight w
__global__ __launch_bounds__(256) void scatter_all(
    const int* __restrict__ ei1, const int* __restrict__ ei2, const int* __restrict__ ei3,
    const float* __restrict__ w1, const float* __restrict__ w2, const float* __restrict__ w3,
    int* __restrict__ cursor_a, int* __restrict__ cursor_q,
    int2* __restrict__ payload_a, int2* __restrict__ payload_q)
{
    const int gid = blockIdx.x * 256 + threadIdx.x;
    const int* src; const int* dst; const float* w;
    int e, stride, kbase, rel; int* cur; int2* pay;
    if (gid < E1n) {
        e = gid; src = ei1; dst = ei1 + E1n; w = w1;
        stride = 320; kbase = 64; rel = 0; cur = cursor_a; pay = payload_a;
    } else if (gid < E1n + E2n) {
        e = gid - E1n; src = ei2; dst = ei2 + E2n; w = w2;
        stride = 320; kbase = 192; rel = 1; cur = cursor_a; pay = payload_a;
    } else if (gid < E1n + E2n + E3n) {
        e = gid - E1n - E2n; src = ei3; dst = ei3 + E3n; w = w3;
        stride = 192; kbase = 64; rel = 0; cur = cursor_q; pay = payload_q;
    } else {
        return;
    }
    const int s = src[e];
    const int d = dst[e];
    if ((unsigned)d >= (unsigned)NQn) return;   // guaranteed not to happen; memory safety
    const int slot = atomicAdd(&cur[d], 1);
    if (slot < SLOTS)
        pay[(size_t)d * SLOTS + slot] =
            make_int2((s * stride + kbase) | rel, __float_as_int(w[e]));
}

// -------- gather + softmax + gelu + MFMA-Wo + skip -------------------------
// Merged A-side + Q-side launch. One node per 8-lane group => 8 concurrent
// edge-chains/wave. 2-deep software pipeline — K/V for edge i+1 issued during
// compute of edge i (payload runs 2 ahead, clamped tail). <=64 VGPR tier.
struct GArgs {
    const int* cursor; const int2* payload; const u16* srcArr;
    const u16* qArr; const u16* h_in;
    const u16* Wof; const float* bo; const float* skip;
    u16* z_out;
    int qStride; int N; int ntiles; int t0; int t1;
};

__global__ __launch_bounds__(256, 8) void gather_finalize(
    GArgs A, GArgs Q, const float* __restrict__ p_rel)
{
    __shared__ __align__(16) short sG[4][16 * 72];     // per-wave gelu rows (bf16)
    __shared__ __align__(16) short sHh[4][16 * 72];    // per-wave h rows -> z rows

    const bool isA = (int)blockIdx.x < A.ntiles;
    const GArgs& G = isA ? A : Q;
    const int tile = isA ? (int)blockIdx.x : (int)blockIdx.x - A.ntiles;

    const int tid = threadIdx.x;
    const int wave = tid >> 6, lane = tid & 63;
    const int quad = lane >> 4, mrow = lane & 15;
    const int grp = lane >> 3;       // node group 0..7
    const int gl = lane & 7;         // lane within group; holds channels 8gl..8gl+7
    const int ghead = gl >> 2;       // head of this lane's channels
    const int prow = lane >> 3;      // store-phase row (8 rows/instr)
    const int pcol = (lane & 7) * 8; // 16-B chunk within 128-B row

    const float sk = sigmoidf_(G.skip[0]);
    const float isq = 0.17677669529663687f;   // 1/sqrt(32)
    const float s0 = p_rel[G.t0 * 2 + ghead] * isq;
    const float s1 = p_rel[G.t1 * 2 + ghead] * isq;

    short* const myG = &sG[wave][0];
    short* const myHh = &sHh[wave][0];

    const int N = G.N;
    const int nbase = tile * 64 + wave * 16;

    // hoisted in-degree loads for both subs (breaks cursor->payload hop)
    int cnt2[2];
    #pragma unroll
    for (int sub = 0; sub < 2; ++sub) {
        const int node = nbase + sub * 8 + grp;
        int c = (node < N && node < NQn) ? G.cursor[node] : 0;
        cnt2[sub] = (c > SLOTS) ? SLOTS : c;
    }

    #pragma unroll
    for (int sub = 0; sub < 2; ++sub) {
        const int nl = sub * 8 + grp;
        const int node = nbase + nl;
        const bool valid = node < N;
        const int cnt = cnt2[sub];
        uint4 qraw = make_uint4(0, 0, 0, 0), hraw = make_uint4(0, 0, 0, 0);
        if (valid) {
            qraw = *(const uint4*)(G.qArr + (size_t)node * G.qStride + gl * 8);
            hraw = *(const uint4*)(G.h_in + (size_t)node * 64 + gl * 8);
        }
        *(uint4*)&myHh[nl * 72 + gl * 8] = hraw;
        const float qv0 = bf2f_lo(qraw.x), qv1 = bf2f_hi(qraw.x);
        const float qv2 = bf2f_lo(qraw.y), qv3 = bf2f_hi(qraw.y);
        const float qv4 = bf2f_lo(qraw.z), qv5 = bf2f_hi(qraw.z);
        const float qv6 = bf2f_lo(qraw.w), qv7 = bf2f_hi(qraw.w);

        const int2* pp = G.payload + (size_t)node * SLOTS;
        float a0 = 0.f, a1 = 0.f, a2 = 0.f, a3 = 0.f;
        float a4 = 0.f, a5 = 0.f, a6 = 0.f, a7 = 0.f, den = 0.f;
        if (cnt > 0) {
            int2 ecur = pp[0];
            int2 enext = pp[(cnt > 1) ? 1 : 0];
            int koff = ecur.x & ~31;
            uint4 kcur = *(const uint4*)(G.srcArr + (size_t)koff + gl * 8);
            uint4 vcur = *(const uint4*)(G.srcArr + (size_t)koff + 64 + gl * 8);
            for (int i = 0; i < cnt; ++i) {
                // prefetch K/V for i+1 (clamped: tail reloads an L1-hot line)
                const int koff2 = enext.x & ~31;
                const uint4 kn = *(const uint4*)(G.srcArr + (size_t)koff2 + gl * 8);
                const uint4 vn = *(const uint4*)(G.srcArr + (size_t)koff2 + 64 + gl * 8);
                const int ip2 = (i + 2 < cnt) ? (i + 2) : (cnt - 1);
                const int2 en3 = pp[ip2];
                // compute edge i
                float p = qv0 * bf2f_lo(kcur.x) + qv1 * bf2f_hi(kcur.x)
                        + qv2 * bf2f_lo(kcur.y) + qv3 * bf2f_hi(kcur.y)
                        + qv4 * bf2f_lo(kcur.z) + qv5 * bf2f_hi(kcur.z)
                        + qv6 * bf2f_lo(kcur.w) + qv7 * bf2f_hi(kcur.w);
                p += __shfl_xor(p, 1);   // reduce over the 4 lanes of this head
                p += __shfl_xor(p, 2);
                const float sc = (ecur.x & 1) ? s1 : s0;
                const float exv = __expf(p * sc);
                const float ew = exv * __int_as_float(ecur.y);
                a0 = fmaf(ew, bf2f_lo(vcur.x), a0); a1 = fmaf(ew, bf2f_hi(vcur.x), a1);
                a2 = fmaf(ew, bf2f_lo(vcur.y), a2); a3 = fmaf(ew, bf2f_hi(vcur.y), a3);
                a4 = fmaf(ew, bf2f_lo(vcur.z), a4); a5 = fmaf(ew, bf2f_hi(vcur.z), a5);
                a6 = fmaf(ew, bf2f_lo(vcur.w), a6); a7 = fmaf(ew, bf2f_hi(vcur.w), a7);
                den += exv;
                // rotate pipeline
                ecur = enext; enext = en3; kcur = kn; vcur = vn;
            }
        }

        const float inv = 1.f / (den + 1e-16f);
        float gv[8] = {a0 * inv, a1 * inv, a2 * inv, a3 * inv,
                       a4 * inv, a5 * inv, a6 * inv, a7 * inv};
        #pragma unroll
        for (int j = 0; j < 8; ++j) {
            const float xx = gv[j];
            const float u = 0.7978845608028654f * (xx + 0.044715f * xx * xx * xx);
            const float th = 1.f - 2.f / (__expf(2.f * u) + 1.f);
            gv[j] = 0.5f * xx * (1.f + th);
        }
        uint4 gp;
        gp.x = (unsigned)f2bf(gv[0]) | ((unsigned)f2bf(gv[1]) << 16);
        gp.y = (unsigned)f2bf(gv[2]) | ((unsigned)f2bf(gv[3]) << 16);
        gp.z = (unsigned)f2bf(gv[4]) | ((unsigned)f2bf(gv[5]) << 16);
        gp.w = (unsigned)f2bf(gv[6]) | ((unsigned)f2bf(gv[7]) << 16);
        *(uint4*)&myG[nl * 72 + gl * 8] = gp;
    }

    // wave-private MFMA: Z16x64 = G16x64 @ Wo64x64 (+bo), skip blend -> myHh
    short8 ag[2];
    #pragma unroll
    for (int kt = 0; kt < 2; ++kt)
        ag[kt] = *(const short8*)&myG[mrow * 72 + kt * 32 + quad * 8];

    #pragma unroll
    for (int nt = 0; nt < 4; ++nt) {
        const float bov = G.bo[nt * 16 + mrow];
        f32x4 acc = {bov, bov, bov, bov};
        const short8 b0 = *(const short8*)&G.Wof[((0 * 4 + nt) * 64 + lane) * 8];
        acc = __builtin_amdgcn_mfma_f32_16x16x32_bf16(ag[0], b0, acc, 0, 0, 0);
        const short8 b1 = *(const short8*)&G.Wof[((1 * 4 + nt) * 64 + lane) * 8];
        acc = __builtin_amdgcn_mfma_f32_16x16x32_bf16(ag[1], b1, acc, 0, 0, 0);
        #pragma unroll
        for (int r = 0; r < 4; ++r) {
            const int row = quad * 4 + r;
            const int a = row * 72 + nt * 16 + mrow;
            const float hv = bf2f((u16)myHh[a]);
            myHh[a] = (short)f2bf(sk * acc[r] + (1.f - sk) * hv);
        }
    }

    // ---- z store: 2 back-to-back instrs, 2 KB contiguous ----
    if (nbase + 16 <= N) {
        const u32x4 w0 = *(const u32x4*)&myHh[prow * 72 + pcol];
        const u32x4 w1 = *(const u32x4*)&myHh[(prow + 8) * 72 + pcol];
        *(u32x4*)(G.z_out + (size_t)(nbase + prow) * 64 + pcol) = w0;
        *(u32x4*)(G.z_out + (size_t)(nbase + prow + 8) * 64 + pcol) = w1;
    } else {
        for (int e2 = lane; e2 < 16 * 64; e2 += 64) {
            const int r = e2 >> 6, c = e2 & 63;
            const int nd = nbase + r;
            if (nd < N) G.z_out[(size_t)nd * 64 + c] = (u16)myHh[r * 72 + c];
        }
    }
}

// -------- decoder: sigmoid(dot64) link prediction --------------------------
__global__ __launch_bounds__(256) void decoder_kernel(
    const u16* __restrict__ z_q, const u16* __restrict__ z_a,
    const int* __restrict__ pos_idx, const int* __restrict__ neg_idx,
    float* __restrict__ out)
{
    const int gid = blockIdx.x * 256 + threadIdx.x;
    const int o = gid >> 5;         // half-wave per output
    if (o >= 2 * NLn) return;
    const int lane = threadIdx.x & 31;
    const int* idx;
    int i;
    if (o < NLn) { idx = pos_idx; i = o; }
    else         { idx = neg_idx; i = o - NLn; }
    const int r0 = idx[i];
    const int r1 = idx[NLn + i];
    const unsigned uq = *(const unsigned*)(z_q + (size_t)r0 * 64 + 2 * lane);
    const unsigned ua = *(const unsigned*)(z_a + (size_t)r1 * 64 + 2 * lane);
    float s = bf2f_lo(uq) * bf2f_lo(ua) + bf2f_hi(uq) * bf2f_hi(ua);
    s += __shfl_xor(s, 16);
    s += __shfl_xor(s, 8);
    s += __shfl_xor(s, 4);
    s += __shfl_xor(s, 2);
    s += __shfl_xor(s, 1);
    if (lane == 0) out[o] = sigmoidf_(s);
}

extern "C" void kernel_launch(void* const* d_in, const int* in_sizes, int n_in,
                              void* d_out, int out_size, void* d_ws, size_t ws_size,
                              hipStream_t stream)
{
    (void)in_sizes; (void)n_in; (void)out_size;
    const float* x_q   = (const float*)d_in[0];
    const float* x_a   = (const float*)d_in[1];
    const int* ei_qca  = (const int*)d_in[2];
    const int* ei_qwa  = (const int*)d_in[3];
    const int* ei_rev  = (const int*)d_in[4];
    const int* pos_idx = (const int*)d_in[5];
    const int* neg_idx = (const int*)d_in[6];
    const float* w_qca = (const float*)d_in[7];
    const float* w_qwa = (const float*)d_in[8];
    const float* w_rev = (const float*)d_in[9];
    const float* W_in_q = (const float*)d_in[10]; const float* b_in_q = (const float*)d_in[11];
    const float* W_in_a = (const float*)d_in[12]; const float* b_in_a = (const float*)d_in[13];
    const float* Wk_qn = (const float*)d_in[14], *bk_qn = (const float*)d_in[15];
    const float* Wq_qn = (const float*)d_in[16], *bq_qn = (const float*)d_in[17];
    const float* Wv_qn = (const float*)d_in[18], *bv_qn = (const float*)d_in[19];
    const float* Wk_an = (const float*)d_in[20], *bk_an = (const float*)d_in[21];
    const float* Wq_an = (const float*)d_in[22], *bq_an = (const float*)d_in[23];
    const float* Wv_an = (const float*)d_in[24], *bv_an = (const float*)d_in[25];
    const float* a_rel = (const float*)d_in[26];
    const float* m_rel = (const float*)d_in[27];
    const float* p_rel = (const float*)d_in[28];
    const float* Wo_qn = (const float*)d_in[29], *bo_qn = (const float*)d_in[30];
    const float* Wo_an = (const float*)d_in[31], *bo_an = (const float*)d_in[32];
    const float* skip_qn = (const float*)d_in[33], *skip_an = (const float*)d_in[34];

    char* ws = (char*)d_ws;
    size_t off = 0;
    auto alloc = [&](size_t bytes) -> char* {
        char* p = ws + off;
        off = (off + bytes + 255) & ~(size_t)255;
        return p;
    };
    u16* big_q = (u16*)alloc((size_t)NQn * 320 * 2);  // q | k0 | v0 | k1 | v1
    u16* big_a = (u16*)alloc((size_t)NAn * 192 * 2);  // q | k2 | v2
    u16* h_q   = (u16*)alloc((size_t)NQn * 64 * 2);
    u16* h_a   = (u16*)alloc((size_t)NAn * 64 * 2);
    u16* z_q   = (u16*)alloc((size_t)NQn * 64 * 2);
    u16* z_a   = (u16*)alloc((size_t)NAn * 64 * 2);
    int2* payload_a = (int2*)alloc((size_t)NQn * SLOTS * 8);  // dst of E1/E2 < NQn
    int2* payload_q = (int2*)alloc((size_t)NQn * SLOTS * 8);
    char* zero_start = ws + off;
    int* cursor_a = (int*)alloc((size_t)NQn * 4);
    int* cursor_q = (int*)alloc((size_t)NQn * 4);
    char* zero_end = ws + off;
    u16* Wbigf_q = (u16*)alloc(64 * 320 * 2);
    float* bbig_q = (float*)alloc(320 * 4);
    u16* Wbigf_a = (u16*)alloc(64 * 192 * 2);
    float* bbig_a = (float*)alloc(192 * 4);
    u16* Wof_a = (u16*)alloc(4096 * 2);
    u16* Wof_q = (u16*)alloc(4096 * 2);
    u16* Winf_q = (u16*)alloc(8192 * 2);
    u16* Winf_a = (u16*)alloc(8192 * 2);

    if (off > ws_size) return;  // workspace too small: leave output zeroed (visible failure)

    hipMemsetAsync(zero_start, 0, (size_t)(zero_end - zero_start), stream);

    fold_kernel<<<64, 256, 0, stream>>>(Wk_qn, Wv_qn, Wq_qn, bk_qn, bv_qn, bq_qn,
                                        a_rel, m_rel, 0, 1, Wbigf_q, bbig_q, 320);
    fold_kernel<<<64, 256, 0, stream>>>(Wk_an, Wv_an, Wq_an, bk_an, bv_an, bq_an,
                                        a_rel, m_rel, 2, -1, Wbigf_a, bbig_a, 192);
    fold_small<<<96, 256, 0, stream>>>(W_in_q, Winf_q, W_in_a, Winf_a,
                                       Wo_an, Wof_a, Wo_qn, Wof_q);

    node_mfma<320><<<768, 256, 0, stream>>>(x_q, NQn, Winf_q, b_in_q,
                                            Wbigf_q, bbig_q, h_q, big_q);
    node_mfma<192><<<1024, 256, 0, stream>>>(x_a, NAn, Winf_a, b_in_a,
                                             Wbigf_a, bbig_a, h_a, big_a);

    scatter_all<<<(E1n + E2n + E3n + 255) / 256, 256, 0, stream>>>(
        ei_qca, ei_qwa, ei_rev, w_qca, w_qwa, w_rev,
        cursor_a, cursor_q, payload_a, payload_q);

    // merged gather: blocks [0, ntA) = answer side, [ntA, ntA+ntQ) = question side
    const int ntA = (NAn + 63) >> 6;   // 3125
    const int ntQ = (NQn + 63) >> 6;   // 1563
    GArgs A, Q;
    A.cursor = cursor_a; A.payload = payload_a; A.srcArr = big_q;
    A.qArr = big_a; A.h_in = h_a; A.Wof = Wof_a; A.bo = bo_an; A.skip = skip_an;
    A.z_out = z_a; A.qStride = 192; A.N = NAn; A.ntiles = ntA; A.t0 = 0; A.t1 = 1;
    Q.cursor = cursor_q; Q.payload = payload_q; Q.srcArr = big_a;
    Q.qArr = big_q; Q.h_in = h_q; Q.Wof = Wof_q; Q.bo = bo_qn; Q.skip = skip_qn;
    Q.z_out = z_q; Q.qStride = 320; Q.N = NQn; Q.ntiles = ntQ; Q.t0 = 2; Q.t1 = 2;
    gather_finalize<<<ntA + ntQ, 256, 0, stream>>>(A, Q, p_rel);

    decoder_kernel<<<(2 * NLn * 32 + 255) / 256, 256, 0, stream>>>(
        z_q, z_a, pos_idx, neg_idx, (float*)d_out);
}

// Round 11
// 472.954 us; speedup vs baseline: 1.1295x; 1.1007x over previous
//
#include <hip/hip_runtime.h>

typedef unsigned short u16;
typedef __attribute__((ext_vector_type(8))) short short8;   // 8 bf16 = 4 VGPRs
typedef __attribute__((ext_vector_type(4))) float f32x4;
typedef __attribute__((ext_vector_type(4))) unsigned int u32x4;

#define NQn 100000
#define NAn 200000
#define E1n 250000
#define E2n 250000
#define E3n 500000
#define NLn 100000
#define SLOTS 40   // max in-degree bucket capacity; Poisson(5) => P(>40) ~ 1e-22

__device__ __forceinline__ float bf2f(u16 u) {
    return __uint_as_float(((unsigned)u) << 16);
}
__device__ __forceinline__ float bf2f_lo(unsigned u) {
    return __uint_as_float(u << 16);
}
__device__ __forceinline__ float bf2f_hi(unsigned u) {
    return __uint_as_float(u & 0xffff0000u);
}
__device__ __forceinline__ u16 f2bf(float f) {
    unsigned x = __float_as_uint(f);
    unsigned r = (x + 0x7fffu + ((x >> 16) & 1u)) >> 16;
    return (u16)r;
}
__device__ __forceinline__ float sigmoidf_(float x) {
    return 1.f / (1.f + __expf(-x));
}

// -------- fold bodies (merged into one launch, r11) ------------------------
// Logical Wbig cols: [0,64): Wq ; [64,128): Wk@A(t0) ; [128,192): Wv@M(t0) ;
//                    [192,256): Wk@A(t1) ; [256,320): Wv@M(t1)
// Fragment layout: Wbigf[(((k>>5)*NT + (col>>4))*64 + ((k&31)>>3)*16 + (col&15))*8 + (k&7)]
__device__ void fold_big_dev(
    const float* __restrict__ Wk, const float* __restrict__ Wv, const float* __restrict__ Wq,
    const float* __restrict__ bk, const float* __restrict__ bv, const float* __restrict__ bq,
    const float* __restrict__ a_rel, const float* __restrict__ m_rel,
    int t0, int t1, u16* __restrict__ Wbigf, float* __restrict__ bbig, int NOUT,
    int bid, int nblocks)
{
    const int NT = NOUT >> 4;
    const int total = 65 * NOUT;   // 64 weight rows + 1 bias row
    for (int idx = bid * 256 + threadIdx.x; idx < total; idx += nblocks * 256) {
        const int c   = idx / NOUT;
        const int col = idx - c * NOUT;
        const int grp = col >> 6;
        const int oc  = col & 63;
        const int h   = oc >> 5, e = oc & 31;
        if (c < 64) {
            float val;
            if (grp == 0) {
                val = Wq[c * 64 + oc];
            } else {
                const int t = (grp <= 2) ? t0 : t1;
                const float* W = (grp & 1) ? Wk : Wv;
                const float* T = (grp & 1) ? a_rel : m_rel;
                float s = 0.f;
                for (int d = 0; d < 32; ++d)
                    s = fmaf(W[c * 64 + h * 32 + d],
                             T[((t * 2 + h) * 32 + d) * 32 + e], s);
                val = s;
            }
            const int fi = (((c >> 5) * NT + (col >> 4)) * 64
                            + ((c & 31) >> 3) * 16 + (col & 15)) * 8 + (c & 7);
            Wbigf[fi] = f2bf(val);
        } else {
            float val;
            if (grp == 0) {
                val = bq[oc];
            } else {
                const int t = (grp <= 2) ? t0 : t1;
                const float* B = (grp & 1) ? bk : bv;
                const float* T = (grp & 1) ? a_rel : m_rel;
                float s = 0.f;
                for (int d = 0; d < 32; ++d)
                    s = fmaf(B[h * 32 + d],
                             T[((t * 2 + h) * 32 + d) * 32 + e], s);
                val = s;
            }
            bbig[col] = val;
        }
    }
}

// Wf[(f*64+ln)*8+j] = W[(kt*32+(ln>>4)*8+j)*64 + nt*16+(ln&15)], f=kt*4+nt
__device__ void fold_small_dev(
    int gid,
    const float* __restrict__ Winq, u16* __restrict__ Winfq,
    const float* __restrict__ Wina, u16* __restrict__ Winfa,
    const float* __restrict__ WoA, u16* __restrict__ WofA,
    const float* __restrict__ WoQ, u16* __restrict__ WofQ)
{
    const float* W; u16* Wf; int t;
    if (gid < 8192)        { W = Winq; Wf = Winfq; t = gid; }
    else if (gid < 16384)  { W = Wina; Wf = Winfa; t = gid - 8192; }
    else if (gid < 20480)  { W = WoA;  Wf = WofA;  t = gid - 16384; }
    else if (gid < 24576)  { W = WoQ;  Wf = WofQ;  t = gid - 20480; }
    else return;
    const int j = t & 7, ln = (t >> 3) & 63, f = t >> 9;
    const int kt = f >> 2, nt = f & 3;
    const int k = kt * 32 + (ln >> 4) * 8 + j;
    const int n = nt * 16 + (ln & 15);
    Wf[t] = f2bf(W[k * 64 + n]);
}

__global__ void fold_all(
    const float* Wk_q, const float* Wv_q, const float* Wq_q,
    const float* bk_q, const float* bv_q, const float* bq_q,
    const float* Wk_a, const float* Wv_a, const float* Wq_a,
    const float* bk_a, const float* bv_a, const float* bq_a,
    const float* a_rel, const float* m_rel,
    u16* Wbigf_q, float* bbig_q, u16* Wbigf_a, float* bbig_a,
    const float* Winq, u16* Winfq, const float* Wina, u16* Winfa,
    const float* WoA, u16* WofA, const float* WoQ, u16* WofQ)
{
    const int b = blockIdx.x;
    if (b < 64) {
        fold_big_dev(Wk_q, Wv_q, Wq_q, bk_q, bv_q, bq_q, a_rel, m_rel,
                     0, 1, Wbigf_q, bbig_q, 320, b, 64);
    } else if (b < 128) {
        fold_big_dev(Wk_a, Wv_a, Wq_a, bk_a, bv_a, bq_a, a_rel, m_rel,
                     2, -1, Wbigf_a, bbig_a, 192, b - 64, 64);
    } else {
        fold_small_dev((b - 128) * 256 + threadIdx.x,
                       Winq, Winfq, Wina, Winfa, WoA, WofA, WoQ, WofQ);
    }
}

// -------- MFMA fused node projection --------------------------------------
// r11: occupancy REVERT. Cross-round ablation (r3 vs r4/r9/r10): traffic is
// clean (WRITE=ideal 100 MB, FETCH=50 — L3 even kept x resident) at 19%
// occupancy, and inflated (+80 MB each way) at 37% — invariant to every
// store-pattern change. The inflation is concurrency-induced L2/L3 churn.
// Restore r2's resource shape: weights in LDS (sB1 via u32x4 memcpy from the
// r4 fragment-folded buffer — keeps the staging win), launch_bounds(256,2),
// grids 512/768 => LDS-capped 2 blocks/CU (NOUT=320, 66.5 KB) and 3 blocks/CU
// (NOUT=192, 50 KB). Plain x loads (L3 residency), plain clustered stores.
template <int NOUT>
__global__ __launch_bounds__(256, 2) void node_mfma(
    const float* __restrict__ x, int N,
    const u16* __restrict__ Winf, const float* __restrict__ bin,
    const u16* __restrict__ Wbigf, const float* __restrict__ bbig,
    u16* __restrict__ h_out, u16* __restrict__ big_out)
{
    constexpr int NT = NOUT / 16;            // stage-2 col tiles
    constexpr int NG = NT / 4;               // stage-2 64-col store groups
    __shared__ __align__(16) short sB1[16 * 64 * 8];      // stage-1 frags, 16 KB
    __shared__ __align__(16) short sB2[2 * NT * 64 * 8];  // stage-2 frags
    __shared__ __align__(16) short sH[4][16 * 72];        // per-wave tile, stride 72

    const int tid = threadIdx.x;
    for (int idx = tid; idx < 16 * 64; idx += 256)
        ((u32x4*)sB1)[idx] = ((const u32x4*)Winf)[idx];
    for (int idx = tid; idx < 2 * NT * 64; idx += 256)
        ((u32x4*)sB2)[idx] = ((const u32x4*)Wbigf)[idx];
    __syncthreads();

    const int wave = tid >> 6;
    const int lane = tid & 63;
    const int quad = lane >> 4;
    const int mrow = lane & 15;
    short* const myH = &sH[wave][0];
    const int prow = lane >> 3;              // store-phase row (8 rows/instr)
    const int pcol = (lane & 7) * 8;         // 16-B chunk within 128-B row

    float bin4[4];
    #pragma unroll
    for (int nt = 0; nt < 4; ++nt) bin4[nt] = bin[nt * 16 + mrow];

    const int ntiles = (N + 63) >> 6;
    for (int tile = blockIdx.x; tile < ntiles; tile += gridDim.x) {
        const int nbase = tile * 64 + wave * 16;
        const int node = nbase + mrow;
        const bool fullgrp = (nbase + 16 <= N);

        short8 a1[4];
        if (node < N) {
            const float* xp = x + (size_t)node * 128 + quad * 8;
            #pragma unroll
            for (int kt = 0; kt < 4; ++kt) {
                const float4 u0 = *(const float4*)(xp + kt * 32);
                const float4 u1 = *(const float4*)(xp + kt * 32 + 4);
                short8 f;
                f[0] = (short)f2bf(u0.x); f[1] = (short)f2bf(u0.y);
                f[2] = (short)f2bf(u0.z); f[3] = (short)f2bf(u0.w);
                f[4] = (short)f2bf(u1.x); f[5] = (short)f2bf(u1.y);
                f[6] = (short)f2bf(u1.z); f[7] = (short)f2bf(u1.w);
                a1[kt] = f;
            }
        } else {
            #pragma unroll
            for (int kt = 0; kt < 4; ++kt) a1[kt] = short8{0,0,0,0,0,0,0,0};
        }

        // ---- stage 1: h = relu(x@Win + b1) -> myH ----
        #pragma unroll
        for (int nt = 0; nt < 4; ++nt) {
            const float bv = bin4[nt];
            f32x4 acc = {bv, bv, bv, bv};
            #pragma unroll
            for (int kt = 0; kt < 4; ++kt) {
                const short8 bf = *(const short8*)&sB1[((kt * 4 + nt) * 64 + lane) * 8];
                acc = __builtin_amdgcn_mfma_f32_16x16x32_bf16(a1[kt], bf, acc, 0, 0, 0);
            }
            #pragma unroll
            for (int r = 0; r < 4; ++r)
                myH[(quad * 4 + r) * 72 + nt * 16 + mrow] =
                    (short)f2bf(fmaxf(acc[r], 0.f));
        }

        // ---- h store: 2 back-to-back instrs, 2 KB contiguous ----
        if (fullgrp) {
            const u32x4 w0 = *(const u32x4*)&myH[prow * 72 + pcol];
            const u32x4 w1 = *(const u32x4*)&myH[(prow + 8) * 72 + pcol];
            *(u32x4*)(h_out + (size_t)(nbase + prow) * 64 + pcol) = w0;
            *(u32x4*)(h_out + (size_t)(nbase + prow + 8) * 64 + pcol) = w1;
        } else {
            for (int e = lane; e < 16 * 64; e += 64) {
                const int r = e >> 6, c = e & 63;
                const int nd = nbase + r;
                if (nd < N) h_out[(size_t)nd * 64 + c] = (u16)myH[r * 72 + c];
            }
        }

        // ---- stage 2: big = h @ Wbig + b2; park store slices in regs ----
        short8 a2[2];
        #pragma unroll
        for (int kt2 = 0; kt2 < 2; ++kt2)
            a2[kt2] = *(const short8*)&myH[mrow * 72 + kt2 * 32 + quad * 8];

        u32x4 sv0[NG], sv1[NG];
        #pragma unroll
        for (int g = 0; g < NG; ++g) {
            #pragma unroll
            for (int q2 = 0; q2 < 4; ++q2) {
                const int nt = g * 4 + q2;
                const float bv = bbig[nt * 16 + mrow];
                f32x4 acc = {bv, bv, bv, bv};
                const short8 b0 = *(const short8*)&sB2[((0 * NT + nt) * 64 + lane) * 8];
                acc = __builtin_amdgcn_mfma_f32_16x16x32_bf16(a2[0], b0, acc, 0, 0, 0);
                const short8 b1 = *(const short8*)&sB2[((1 * NT + nt) * 64 + lane) * 8];
                acc = __builtin_amdgcn_mfma_f32_16x16x32_bf16(a2[1], b1, acc, 0, 0, 0);
                #pragma unroll
                for (int r = 0; r < 4; ++r)
                    myH[(quad * 4 + r) * 72 + q2 * 16 + mrow] = (short)f2bf(acc[r]);
            }
            sv0[g] = *(const u32x4*)&myH[prow * 72 + pcol];
            sv1[g] = *(const u32x4*)&myH[(prow + 8) * 72 + pcol];
        }
        // clustered big store: each row's full extent in consecutive instrs
        if (fullgrp) {
            u16* const rb0 = big_out + (size_t)(nbase + prow) * NOUT + pcol;
            #pragma unroll
            for (int g = 0; g < NG; ++g)
                *(u32x4*)(rb0 + g * 64) = sv0[g];
            u16* const rb1 = big_out + (size_t)(nbase + prow + 8) * NOUT + pcol;
            #pragma unroll
            for (int g = 0; g < NG; ++g)
                *(u32x4*)(rb1 + g * 64) = sv1[g];
        } else {
            #pragma unroll
            for (int g = 0; g < NG; ++g) {
                const int nd0 = nbase + prow;
                if (nd0 < N)
                    *(u32x4*)(big_out + (size_t)nd0 * NOUT + g * 64 + pcol) = sv0[g];
                const int nd1 = nbase + prow + 8;
                if (nd1 < N)
                    *(u32x4*)(big_out + (size_t)nd1 * NOUT + g * 64 + pcol) = sv1[g];
            }
        }
    }
}

// -------- merged scatter: bucket all 3 relations in one launch -------------
// payload.x = (src*srcStride + kBase) | relBit   (k-offset, mult of 32; v = +64)
// payload.y = bits of per-edge weight w
__global__ __launch_bounds__(256) void scatter_all(
    const int* __restrict__ ei1, const int* __restrict__ ei2, const int* __restrict__ ei3,
    const float* __restrict__ w1, const float* __restrict__ w2, const float* __restrict__ w3,
    int* __restrict__ cursor_a, int* __restrict__ cursor_q,
    int2* __restrict__ payload_a, int2* __restrict__ payload_q)
{
    const int gid = blockIdx.x * 256 + threadIdx.x;
    const int* src; const int* dst; const float* w;
    int e, stride, kbase, rel; int* cur; int2* pay;
    if (gid < E1n) {
        e = gid; src = ei1; dst = ei1 + E1n; w = w1;
        stride = 320; kbase = 64; rel = 0; cur = cursor_a; pay = payload_a;
    } else if (gid < E1n + E2n) {
        e = gid - E1n; src = ei2; dst = ei2 + E2n; w = w2;
        stride = 320; kbase = 192; rel = 1; cur = cursor_a; pay = payload_a;
    } else if (gid < E1n + E2n + E3n) {
        e = gid - E1n - E2n; src = ei3; dst = ei3 + E3n; w = w3;
        stride = 192; kbase = 64; rel = 0; cur = cursor_q; pay = payload_q;
    } else {
        return;
    }
    const int s = src[e];
    const int d = dst[e];
    if ((unsigned)d >= (unsigned)NQn) return;   // guaranteed not to happen; memory safety
    const int slot = atomicAdd(&cur[d], 1);
    if (slot < SLOTS)
        pay[(size_t)d * SLOTS + slot] =
            make_int2((s * stride + kbase) | rel, __float_as_int(w[e]));
}

// -------- gather + softmax + gelu + MFMA-Wo + skip -------------------------
// Merged A-side + Q-side launch. One node per 8-lane group => 8 concurrent
// edge-chains/wave. 2-deep software pipeline — K/V for edge i+1 issued during
// compute of edge i (payload runs 2 ahead, clamped tail). <=64 VGPR tier.
struct GArgs {
    const int* cursor; const int2* payload; const u16* srcArr;
    const u16* qArr; const u16* h_in;
    const u16* Wof; const float* bo; const float* skip;
    u16* z_out;
    int qStride; int N; int ntiles; int t0; int t1;
};

__global__ __launch_bounds__(256, 8) void gather_finalize(
    GArgs A, GArgs Q, const float* __restrict__ p_rel)
{
    __shared__ __align__(16) short sG[4][16 * 72];     // per-wave gelu rows (bf16)
    __shared__ __align__(16) short sHh[4][16 * 72];    // per-wave h rows -> z rows

    const bool isA = (int)blockIdx.x < A.ntiles;
    const GArgs& G = isA ? A : Q;
    const int tile = isA ? (int)blockIdx.x : (int)blockIdx.x - A.ntiles;

    const int tid = threadIdx.x;
    const int wave = tid >> 6, lane = tid & 63;
    const int quad = lane >> 4, mrow = lane & 15;
    const int grp = lane >> 3;       // node group 0..7
    const int gl = lane & 7;         // lane within group; holds channels 8gl..8gl+7
    const int ghead = gl >> 2;       // head of this lane's channels
    const int prow = lane >> 3;      // store-phase row (8 rows/instr)
    const int pcol = (lane & 7) * 8; // 16-B chunk within 128-B row

    const float sk = sigmoidf_(G.skip[0]);
    const float isq = 0.17677669529663687f;   // 1/sqrt(32)
    const float s0 = p_rel[G.t0 * 2 + ghead] * isq;
    const float s1 = p_rel[G.t1 * 2 + ghead] * isq;

    short* const myG = &sG[wave][0];
    short* const myHh = &sHh[wave][0];

    const int N = G.N;
    const int nbase = tile * 64 + wave * 16;

    // hoisted in-degree loads for both subs (breaks cursor->payload hop)
    int cnt2[2];
    #pragma unroll
    for (int sub = 0; sub < 2; ++sub) {
        const int node = nbase + sub * 8 + grp;
        int c = (node < N && node < NQn) ? G.cursor[node] : 0;
        cnt2[sub] = (c > SLOTS) ? SLOTS : c;
    }

    #pragma unroll
    for (int sub = 0; sub < 2; ++sub) {
        const int nl = sub * 8 + grp;
        const int node = nbase + nl;
        const bool valid = node < N;
        const int cnt = cnt2[sub];
        uint4 qraw = make_uint4(0, 0, 0, 0), hraw = make_uint4(0, 0, 0, 0);
        if (valid) {
            qraw = *(const uint4*)(G.qArr + (size_t)node * G.qStride + gl * 8);
            hraw = *(const uint4*)(G.h_in + (size_t)node * 64 + gl * 8);
        }
        *(uint4*)&myHh[nl * 72 + gl * 8] = hraw;
        const float qv0 = bf2f_lo(qraw.x), qv1 = bf2f_hi(qraw.x);
        const float qv2 = bf2f_lo(qraw.y), qv3 = bf2f_hi(qraw.y);
        const float qv4 = bf2f_lo(qraw.z), qv5 = bf2f_hi(qraw.z);
        const float qv6 = bf2f_lo(qraw.w), qv7 = bf2f_hi(qraw.w);

        const int2* pp = G.payload + (size_t)node * SLOTS;
        float a0 = 0.f, a1 = 0.f, a2 = 0.f, a3 = 0.f;
        float a4 = 0.f, a5 = 0.f, a6 = 0.f, a7 = 0.f, den = 0.f;
        if (cnt > 0) {
            int2 ecur = pp[0];
            int2 enext = pp[(cnt > 1) ? 1 : 0];
            int koff = ecur.x & ~31;
            uint4 kcur = *(const uint4*)(G.srcArr + (size_t)koff + gl * 8);
            uint4 vcur = *(const uint4*)(G.srcArr + (size_t)koff + 64 + gl * 8);
            for (int i = 0; i < cnt; ++i) {
                // prefetch K/V for i+1 (clamped: tail reloads an L1-hot line)
                const int koff2 = enext.x & ~31;
                const uint4 kn = *(const uint4*)(G.srcArr + (size_t)koff2 + gl * 8);
                const uint4 vn = *(const uint4*)(G.srcArr + (size_t)koff2 + 64 + gl * 8);
                const int ip2 = (i + 2 < cnt) ? (i + 2) : (cnt - 1);
                const int2 en3 = pp[ip2];
                // compute edge i
                float p = qv0 * bf2f_lo(kcur.x) + qv1 * bf2f_hi(kcur.x)
                        + qv2 * bf2f_lo(kcur.y) + qv3 * bf2f_hi(kcur.y)
                        + qv4 * bf2f_lo(kcur.z) + qv5 * bf2f_hi(kcur.z)
                        + qv6 * bf2f_lo(kcur.w) + qv7 * bf2f_hi(kcur.w);
                p += __shfl_xor(p, 1);   // reduce over the 4 lanes of this head
                p += __shfl_xor(p, 2);
                const float sc = (ecur.x & 1) ? s1 : s0;
                const float exv = __expf(p * sc);
                const float ew = exv * __int_as_float(ecur.y);
                a0 = fmaf(ew, bf2f_lo(vcur.x), a0); a1 = fmaf(ew, bf2f_hi(vcur.x), a1);
                a2 = fmaf(ew, bf2f_lo(vcur.y), a2); a3 = fmaf(ew, bf2f_hi(vcur.y), a3);
                a4 = fmaf(ew, bf2f_lo(vcur.z), a4); a5 = fmaf(ew, bf2f_hi(vcur.z), a5);
                a6 = fmaf(ew, bf2f_lo(vcur.w), a6); a7 = fmaf(ew, bf2f_hi(vcur.w), a7);
                den += exv;
                // rotate pipeline
                ecur = enext; enext = en3; kcur = kn; vcur = vn;
            }
        }

        const float inv = 1.f / (den + 1e-16f);
        float gv[8] = {a0 * inv, a1 * inv, a2 * inv, a3 * inv,
                       a4 * inv, a5 * inv, a6 * inv, a7 * inv};
        #pragma unroll
        for (int j = 0; j < 8; ++j) {
            const float xx = gv[j];
            const float u = 0.7978845608028654f * (xx + 0.044715f * xx * xx * xx);
            const float th = 1.f - 2.f / (__expf(2.f * u) + 1.f);
            gv[j] = 0.5f * xx * (1.f + th);
        }
        uint4 gp;
        gp.x = (unsigned)f2bf(gv[0]) | ((unsigned)f2bf(gv[1]) << 16);
        gp.y = (unsigned)f2bf(gv[2]) | ((unsigned)f2bf(gv[3]) << 16);
        gp.z = (unsigned)f2bf(gv[4]) | ((unsigned)f2bf(gv[5]) << 16);
        gp.w = (unsigned)f2bf(gv[6]) | ((unsigned)f2bf(gv[7]) << 16);
        *(uint4*)&myG[nl * 72 + gl * 8] = gp;
    }

    // wave-private MFMA: Z16x64 = G16x64 @ Wo64x64 (+bo), skip blend -> myHh
    short8 ag[2];
    #pragma unroll
    for (int kt = 0; kt < 2; ++kt)
        ag[kt] = *(const short8*)&myG[mrow * 72 + kt * 32 + quad * 8];

    #pragma unroll
    for (int nt = 0; nt < 4; ++nt) {
        const float bov = G.bo[nt * 16 + mrow];
        f32x4 acc = {bov, bov, bov, bov};
        const short8 b0 = *(const short8*)&G.Wof[((0 * 4 + nt) * 64 + lane) * 8];
        acc = __builtin_amdgcn_mfma_f32_16x16x32_bf16(ag[0], b0, acc, 0, 0, 0);
        const short8 b1 = *(const short8*)&G.Wof[((1 * 4 + nt) * 64 + lane) * 8];
        acc = __builtin_amdgcn_mfma_f32_16x16x32_bf16(ag[1], b1, acc, 0, 0, 0);
        #pragma unroll
        for (int r = 0; r < 4; ++r) {
            const int row = quad * 4 + r;
            const int a = row * 72 + nt * 16 + mrow;
            const float hv = bf2f((u16)myHh[a]);
            myHh[a] = (short)f2bf(sk * acc[r] + (1.f - sk) * hv);
        }
    }

    // ---- z store: 2 back-to-back instrs, 2 KB contiguous ----
    if (nbase + 16 <= N) {
        const u32x4 w0 = *(const u32x4*)&myHh[prow * 72 + pcol];
        const u32x4 w1 = *(const u32x4*)&myHh[(prow + 8) * 72 + pcol];
        *(u32x4*)(G.z_out + (size_t)(nbase + prow) * 64 + pcol) = w0;
        *(u32x4*)(G.z_out + (size_t)(nbase + prow + 8) * 64 + pcol) = w1;
    } else {
        for (int e2 = lane; e2 < 16 * 64; e2 += 64) {
            const int r = e2 >> 6, c = e2 & 63;
            const int nd = nbase + r;
            if (nd < N) G.z_out[(size_t)nd * 64 + c] = (u16)myHh[r * 72 + c];
        }
    }
}

// -------- decoder: sigmoid(dot64) link prediction --------------------------
__global__ __launch_bounds__(256) void decoder_kernel(
    const u16* __restrict__ z_q, const u16* __restrict__ z_a,
    const int* __restrict__ pos_idx, const int* __restrict__ neg_idx,
    float* __restrict__ out)
{
    const int gid = blockIdx.x * 256 + threadIdx.x;
    const int o = gid >> 5;         // half-wave per output
    if (o >= 2 * NLn) return;
    const int lane = threadIdx.x & 31;
    const int* idx;
    int i;
    if (o < NLn) { idx = pos_idx; i = o; }
    else         { idx = neg_idx; i = o - NLn; }
    const int r0 = idx[i];
    const int r1 = idx[NLn + i];
    const unsigned uq = *(const unsigned*)(z_q + (size_t)r0 * 64 + 2 * lane);
    const unsigned ua = *(const unsigned*)(z_a + (size_t)r1 * 64 + 2 * lane);
    float s = bf2f_lo(uq) * bf2f_lo(ua) + bf2f_hi(uq) * bf2f_hi(ua);
    s += __shfl_xor(s, 16);
    s += __shfl_xor(s, 8);
    s += __shfl_xor(s, 4);
    s += __shfl_xor(s, 2);
    s += __shfl_xor(s, 1);
    if (lane == 0) out[o] = sigmoidf_(s);
}

extern "C" void kernel_launch(void* const* d_in, const int* in_sizes, int n_in,
                              void* d_out, int out_size, void* d_ws, size_t ws_size,
                              hipStream_t stream)
{
    (void)in_sizes; (void)n_in; (void)out_size;
    const float* x_q   = (const float*)d_in[0];
    const float* x_a   = (const float*)d_in[1];
    const int* ei_qca  = (const int*)d_in[2];
    const int* ei_qwa  = (const int*)d_in[3];
    const int* ei_rev  = (const int*)d_in[4];
    const int* pos_idx = (const int*)d_in[5];
    const int* neg_idx = (const int*)d_in[6];
    const float* w_qca = (const float*)d_in[7];
    const float* w_qwa = (const float*)d_in[8];
    const float* w_rev = (const float*)d_in[9];
    const float* W_in_q = (const float*)d_in[10]; const float* b_in_q = (const float*)d_in[11];
    const float* W_in_a = (const float*)d_in[12]; const float* b_in_a = (const float*)d_in[13];
    const float* Wk_qn = (const float*)d_in[14], *bk_qn = (const float*)d_in[15];
    const float* Wq_qn = (const float*)d_in[16], *bq_qn = (const float*)d_in[17];
    const float* Wv_qn = (const float*)d_in[18], *bv_qn = (const float*)d_in[19];
    const float* Wk_an = (const float*)d_in[20], *bk_an = (const float*)d_in[21];
    const float* Wq_an = (const float*)d_in[22], *bq_an = (const float*)d_in[23];
    const float* Wv_an = (const float*)d_in[24], *bv_an = (const float*)d_in[25];
    const float* a_rel = (const float*)d_in[26];
    const float* m_rel = (const float*)d_in[27];
    const float* p_rel = (const float*)d_in[28];
    const float* Wo_qn = (const float*)d_in[29], *bo_qn = (const float*)d_in[30];
    const float* Wo_an = (const float*)d_in[31], *bo_an = (const float*)d_in[32];
    const float* skip_qn = (const float*)d_in[33], *skip_an = (const float*)d_in[34];

    char* ws = (char*)d_ws;
    size_t off = 0;
    auto alloc = [&](size_t bytes) -> char* {
        char* p = ws + off;
        off = (off + bytes + 255) & ~(size_t)255;
        return p;
    };
    u16* big_q = (u16*)alloc((size_t)NQn * 320 * 2);  // q | k0 | v0 | k1 | v1
    u16* big_a = (u16*)alloc((size_t)NAn * 192 * 2);  // q | k2 | v2
    u16* h_q   = (u16*)alloc((size_t)NQn * 64 * 2);
    u16* h_a   = (u16*)alloc((size_t)NAn * 64 * 2);
    u16* z_q   = (u16*)alloc((size_t)NQn * 64 * 2);
    u16* z_a   = (u16*)alloc((size_t)NAn * 64 * 2);
    int2* payload_a = (int2*)alloc((size_t)NQn * SLOTS * 8);  // dst of E1/E2 < NQn
    int2* payload_q = (int2*)alloc((size_t)NQn * SLOTS * 8);
    char* zero_start = ws + off;
    int* cursor_a = (int*)alloc((size_t)NQn * 4);
    int* cursor_q = (int*)alloc((size_t)NQn * 4);
    char* zero_end = ws + off;
    u16* Wbigf_q = (u16*)alloc(64 * 320 * 2);
    float* bbig_q = (float*)alloc(320 * 4);
    u16* Wbigf_a = (u16*)alloc(64 * 192 * 2);
    float* bbig_a = (float*)alloc(192 * 4);
    u16* Wof_a = (u16*)alloc(4096 * 2);
    u16* Wof_q = (u16*)alloc(4096 * 2);
    u16* Winf_q = (u16*)alloc(8192 * 2);
    u16* Winf_a = (u16*)alloc(8192 * 2);

    if (off > ws_size) return;  // workspace too small: leave output zeroed (visible failure)

    hipMemsetAsync(zero_start, 0, (size_t)(zero_end - zero_start), stream);

    fold_all<<<224, 256, 0, stream>>>(
        Wk_qn, Wv_qn, Wq_qn, bk_qn, bv_qn, bq_qn,
        Wk_an, Wv_an, Wq_an, bk_an, bv_an, bq_an,
        a_rel, m_rel,
        Wbigf_q, bbig_q, Wbigf_a, bbig_a,
        W_in_q, Winf_q, W_in_a, Winf_a,
        Wo_an, Wof_a, Wo_qn, Wof_q);

    node_mfma<320><<<512, 256, 0, stream>>>(x_q, NQn, Winf_q, b_in_q,
                                            Wbigf_q, bbig_q, h_q, big_q);
    node_mfma<192><<<768, 256, 0, stream>>>(x_a, NAn, Winf_a, b_in_a,
                                            Wbigf_a, bbig_a, h_a, big_a);

    scatter_all<<<(E1n + E2n + E3n + 255) / 256, 256, 0, stream>>>(
        ei_qca, ei_qwa, ei_rev, w_qca, w_qwa, w_rev,
        cursor_a, cursor_q, payload_a, payload_q);

    // merged gather: blocks [0, ntA) = answer side, [ntA, ntA+ntQ) = question side
    const int ntA = (NAn + 63) >> 6;   // 3125
    const int ntQ = (NQn + 63) >> 6;   // 1563
    GArgs A, Q;
    A.cursor = cursor_a; A.payload = payload_a; A.srcArr = big_q;
    A.qArr = big_a; A.h_in = h_a; A.Wof = Wof_a; A.bo = bo_an; A.skip = skip_an;
    A.z_out = z_a; A.qStride = 192; A.N = NAn; A.ntiles = ntA; A.t0 = 0; A.t1 = 1;
    Q.cursor = cursor_q; Q.payload = payload_q; Q.srcArr = big_a;
    Q.qArr = big_q; Q.h_in = h_q; Q.Wof = Wof_q; Q.bo = bo_qn; Q.skip = skip_qn;
    Q.z_out = z_q; Q.qStride = 320; Q.N = NQn; Q.ntiles = ntQ; Q.t0 = 2; Q.t1 = 2;
    gather_finalize<<<ntA + ntQ, 256, 0, stream>>>(A, Q, p_rel);

    decoder_kernel<<<(2 * NLn * 32 + 255) / 256, 256, 0, stream>>>(
        z_q, z_a, pos_idx, neg_idx, (float*)d_out);
}

// Round 12
// 466.232 us; speedup vs baseline: 1.1458x; 1.0144x over previous
//
#include <hip/hip_runtime.h>

typedef unsigned short u16;
typedef __attribute__((ext_vector_type(8))) short short8;   // 8 bf16 = 4 VGPRs
typedef __attribute__((ext_vector_type(4))) float f32x4;
typedef __attribute__((ext_vector_type(4))) unsigned int u32x4;

#define NQn 100000
#define NAn 200000
#define E1n 250000
#define E2n 250000
#define E3n 500000
#define NLn 100000
#define SLOTS 40   // max in-degree bucket capacity; Poisson(5) => P(>40) ~ 1e-22

__device__ __forceinline__ float bf2f(u16 u) {
    return __uint_as_float(((unsigned)u) << 16);
}
__device__ __forceinline__ float bf2f_lo(unsigned u) {
    return __uint_as_float(u << 16);
}
__device__ __forceinline__ float bf2f_hi(unsigned u) {
    return __uint_as_float(u & 0xffff0000u);
}
__device__ __forceinline__ u16 f2bf(float f) {
    unsigned x = __float_as_uint(f);
    unsigned r = (x + 0x7fffu + ((x >> 16) & 1u)) >> 16;
    return (u16)r;
}
__device__ __forceinline__ float sigmoidf_(float x) {
    return 1.f / (1.f + __expf(-x));
}

// -------- prep kernel: weight folds + edge scatter in ONE launch (r12) -----
// Blocks [0,64): fold big_q ; [64,128): fold big_a ; [128,224): fold small ;
// [224, 224+ceil(1M/256)): scatter. All independent; saves a launch boundary
// and hides the small folds under the scatter.
// Logical Wbig cols: [0,64): Wq ; [64,128): Wk@A(t0) ; [128,192): Wv@M(t0) ;
//                    [192,256): Wk@A(t1) ; [256,320): Wv@M(t1)
// Fragment layout: Wbigf[(((k>>5)*NT + (col>>4))*64 + ((k&31)>>3)*16 + (col&15))*8 + (k&7)]
__device__ void fold_big_dev(
    const float* __restrict__ Wk, const float* __restrict__ Wv, const float* __restrict__ Wq,
    const float* __restrict__ bk, const float* __restrict__ bv, const float* __restrict__ bq,
    const float* __restrict__ a_rel, const float* __restrict__ m_rel,
    int t0, int t1, u16* __restrict__ Wbigf, float* __restrict__ bbig, int NOUT,
    int bid, int nblocks)
{
    const int NT = NOUT >> 4;
    const int total = 65 * NOUT;   // 64 weight rows + 1 bias row
    for (int idx = bid * 256 + threadIdx.x; idx < total; idx += nblocks * 256) {
        const int c   = idx / NOUT;
        const int col = idx - c * NOUT;
        const int grp = col >> 6;
        const int oc  = col & 63;
        const int h   = oc >> 5, e = oc & 31;
        if (c < 64) {
            float val;
            if (grp == 0) {
                val = Wq[c * 64 + oc];
            } else {
                const int t = (grp <= 2) ? t0 : t1;
                const float* W = (grp & 1) ? Wk : Wv;
                const float* T = (grp & 1) ? a_rel : m_rel;
                float s = 0.f;
                for (int d = 0; d < 32; ++d)
                    s = fmaf(W[c * 64 + h * 32 + d],
                             T[((t * 2 + h) * 32 + d) * 32 + e], s);
                val = s;
            }
            const int fi = (((c >> 5) * NT + (col >> 4)) * 64
                            + ((c & 31) >> 3) * 16 + (col & 15)) * 8 + (c & 7);
            Wbigf[fi] = f2bf(val);
        } else {
            float val;
            if (grp == 0) {
                val = bq[oc];
            } else {
                const int t = (grp <= 2) ? t0 : t1;
                const float* B = (grp & 1) ? bk : bv;
                const float* T = (grp & 1) ? a_rel : m_rel;
                float s = 0.f;
                for (int d = 0; d < 32; ++d)
                    s = fmaf(B[h * 32 + d],
                             T[((t * 2 + h) * 32 + d) * 32 + e], s);
                val = s;
            }
            bbig[col] = val;
        }
    }
}

// Wf[(f*64+ln)*8+j] = W[(kt*32+(ln>>4)*8+j)*64 + nt*16+(ln&15)], f=kt*4+nt
__device__ void fold_small_dev(
    int gid,
    const float* __restrict__ Winq, u16* __restrict__ Winfq,
    const float* __restrict__ Wina, u16* __restrict__ Winfa,
    const float* __restrict__ WoA, u16* __restrict__ WofA,
    const float* __restrict__ WoQ, u16* __restrict__ WofQ)
{
    const float* W; u16* Wf; int t;
    if (gid < 8192)        { W = Winq; Wf = Winfq; t = gid; }
    else if (gid < 16384)  { W = Wina; Wf = Winfa; t = gid - 8192; }
    else if (gid < 20480)  { W = WoA;  Wf = WofA;  t = gid - 16384; }
    else if (gid < 24576)  { W = WoQ;  Wf = WofQ;  t = gid - 20480; }
    else return;
    const int j = t & 7, ln = (t >> 3) & 63, f = t >> 9;
    const int kt = f >> 2, nt = f & 3;
    const int k = kt * 32 + (ln >> 4) * 8 + j;
    const int n = nt * 16 + (ln & 15);
    Wf[t] = f2bf(W[k * 64 + n]);
}

// payload.x = (src*srcStride + kBase) | relBit   (k-offset, mult of 32; v = +64)
// payload.y = bits of per-edge weight w
__device__ void scatter_dev(
    int gid,
    const int* __restrict__ ei1, const int* __restrict__ ei2, const int* __restrict__ ei3,
    const float* __restrict__ w1, const float* __restrict__ w2, const float* __restrict__ w3,
    int* __restrict__ cursor_a, int* __restrict__ cursor_q,
    int2* __restrict__ payload_a, int2* __restrict__ payload_q)
{
    const int* src; const int* dst; const float* w;
    int e, stride, kbase, rel; int* cur; int2* pay;
    if (gid < E1n) {
        e = gid; src = ei1; dst = ei1 + E1n; w = w1;
        stride = 320; kbase = 64; rel = 0; cur = cursor_a; pay = payload_a;
    } else if (gid < E1n + E2n) {
        e = gid - E1n; src = ei2; dst = ei2 + E2n; w = w2;
        stride = 320; kbase = 192; rel = 1; cur = cursor_a; pay = payload_a;
    } else if (gid < E1n + E2n + E3n) {
        e = gid - E1n - E2n; src = ei3; dst = ei3 + E3n; w = w3;
        stride = 192; kbase = 64; rel = 0; cur = cursor_q; pay = payload_q;
    } else {
        return;
    }
    const int s = src[e];
    const int d = dst[e];
    if ((unsigned)d >= (unsigned)NQn) return;   // guaranteed not to happen; memory safety
    const int slot = atomicAdd(&cur[d], 1);
    if (slot < SLOTS)
        pay[(size_t)d * SLOTS + slot] =
            make_int2((s * stride + kbase) | rel, __float_as_int(w[e]));
}

__global__ __launch_bounds__(256) void prep_kernel(
    const float* Wk_q, const float* Wv_q, const float* Wq_q,
    const float* bk_q, const float* bv_q, const float* bq_q,
    const float* Wk_a, const float* Wv_a, const float* Wq_a,
    const float* bk_a, const float* bv_a, const float* bq_a,
    const float* a_rel, const float* m_rel,
    u16* Wbigf_q, float* bbig_q, u16* Wbigf_a, float* bbig_a,
    const float* Winq, u16* Winfq, const float* Wina, u16* Winfa,
    const float* WoA, u16* WofA, const float* WoQ, u16* WofQ,
    const int* ei1, const int* ei2, const int* ei3,
    const float* w1, const float* w2, const float* w3,
    int* cursor_a, int* cursor_q, int2* payload_a, int2* payload_q)
{
    const int b = blockIdx.x;
    if (b < 64) {
        fold_big_dev(Wk_q, Wv_q, Wq_q, bk_q, bv_q, bq_q, a_rel, m_rel,
                     0, 1, Wbigf_q, bbig_q, 320, b, 64);
    } else if (b < 128) {
        fold_big_dev(Wk_a, Wv_a, Wq_a, bk_a, bv_a, bq_a, a_rel, m_rel,
                     2, -1, Wbigf_a, bbig_a, 192, b - 64, 64);
    } else if (b < 224) {
        fold_small_dev((b - 128) * 256 + threadIdx.x,
                       Winq, Winfq, Wina, Winfa, WoA, WofA, WoQ, WofQ);
    } else {
        scatter_dev((b - 224) * 256 + threadIdx.x,
                    ei1, ei2, ei3, w1, w2, w3,
                    cursor_a, cursor_q, payload_a, payload_q);
    }
}

// -------- MFMA fused node projection (r11-proven shape, unchanged) ---------
// Occupancy kept LOW on purpose (cross-round ablation r3 vs r4/r9/r10):
// traffic is clean at ~19% occupancy and inflates +80 MB each way at 37% —
// concurrency-induced L2/L3 churn. Weights staged in LDS from pre-folded
// fragment buffers (pure u32x4 memcpy); launch_bounds(256,2); grids 512/768.
template <int NOUT>
__global__ __launch_bounds__(256, 2) void node_mfma(
    const float* __restrict__ x, int N,
    const u16* __restrict__ Winf, const float* __restrict__ bin,
    const u16* __restrict__ Wbigf, const float* __restrict__ bbig,
    u16* __restrict__ h_out, u16* __restrict__ big_out)
{
    constexpr int NT = NOUT / 16;            // stage-2 col tiles
    constexpr int NG = NT / 4;               // stage-2 64-col store groups
    __shared__ __align__(16) short sB1[16 * 64 * 8];      // stage-1 frags, 16 KB
    __shared__ __align__(16) short sB2[2 * NT * 64 * 8];  // stage-2 frags
    __shared__ __align__(16) short sH[4][16 * 72];        // per-wave tile, stride 72

    const int tid = threadIdx.x;
    for (int idx = tid; idx < 16 * 64; idx += 256)
        ((u32x4*)sB1)[idx] = ((const u32x4*)Winf)[idx];
    for (int idx = tid; idx < 2 * NT * 64; idx += 256)
        ((u32x4*)sB2)[idx] = ((const u32x4*)Wbigf)[idx];
    __syncthreads();

    const int wave = tid >> 6;
    const int lane = tid & 63;
    const int quad = lane >> 4;
    const int mrow = lane & 15;
    short* const myH = &sH[wave][0];
    const int prow = lane >> 3;              // store-phase row (8 rows/instr)
    const int pcol = (lane & 7) * 8;         // 16-B chunk within 128-B row

    float bin4[4];
    #pragma unroll
    for (int nt = 0; nt < 4; ++nt) bin4[nt] = bin[nt * 16 + mrow];

    const int ntiles = (N + 63) >> 6;
    for (int tile = blockIdx.x; tile < ntiles; tile += gridDim.x) {
        const int nbase = tile * 64 + wave * 16;
        const int node = nbase + mrow;
        const bool fullgrp = (nbase + 16 <= N);

        short8 a1[4];
        if (node < N) {
            const float* xp = x + (size_t)node * 128 + quad * 8;
            #pragma unroll
            for (int kt = 0; kt < 4; ++kt) {
                const float4 u0 = *(const float4*)(xp + kt * 32);
                const float4 u1 = *(const float4*)(xp + kt * 32 + 4);
                short8 f;
                f[0] = (short)f2bf(u0.x); f[1] = (short)f2bf(u0.y);
                f[2] = (short)f2bf(u0.z); f[3] = (short)f2bf(u0.w);
                f[4] = (short)f2bf(u1.x); f[5] = (short)f2bf(u1.y);
                f[6] = (short)f2bf(u1.z); f[7] = (short)f2bf(u1.w);
                a1[kt] = f;
            }
        } else {
            #pragma unroll
            for (int kt = 0; kt < 4; ++kt) a1[kt] = short8{0,0,0,0,0,0,0,0};
        }

        // ---- stage 1: h = relu(x@Win + b1) -> myH ----
        #pragma unroll
        for (int nt = 0; nt < 4; ++nt) {
            const float bv = bin4[nt];
            f32x4 acc = {bv, bv, bv, bv};
            #pragma unroll
            for (int kt = 0; kt < 4; ++kt) {
                const short8 bf = *(const short8*)&sB1[((kt * 4 + nt) * 64 + lane) * 8];
                acc = __builtin_amdgcn_mfma_f32_16x16x32_bf16(a1[kt], bf, acc, 0, 0, 0);
            }
            #pragma unroll
            for (int r = 0; r < 4; ++r)
                myH[(quad * 4 + r) * 72 + nt * 16 + mrow] =
                    (short)f2bf(fmaxf(acc[r], 0.f));
        }

        // ---- h store: 2 back-to-back instrs, 2 KB contiguous ----
        if (fullgrp) {
            const u32x4 w0 = *(const u32x4*)&myH[prow * 72 + pcol];
            const u32x4 w1 = *(const u32x4*)&myH[(prow + 8) * 72 + pcol];
            *(u32x4*)(h_out + (size_t)(nbase + prow) * 64 + pcol) = w0;
            *(u32x4*)(h_out + (size_t)(nbase + prow + 8) * 64 + pcol) = w1;
        } else {
            for (int e = lane; e < 16 * 64; e += 64) {
                const int r = e >> 6, c = e & 63;
                const int nd = nbase + r;
                if (nd < N) h_out[(size_t)nd * 64 + c] = (u16)myH[r * 72 + c];
            }
        }

        // ---- stage 2: big = h @ Wbig + b2; park store slices in regs ----
        short8 a2[2];
        #pragma unroll
        for (int kt2 = 0; kt2 < 2; ++kt2)
            a2[kt2] = *(const short8*)&myH[mrow * 72 + kt2 * 32 + quad * 8];

        u32x4 sv0[NG], sv1[NG];
        #pragma unroll
        for (int g = 0; g < NG; ++g) {
            #pragma unroll
            for (int q2 = 0; q2 < 4; ++q2) {
                const int nt = g * 4 + q2;
                const float bv = bbig[nt * 16 + mrow];
                f32x4 acc = {bv, bv, bv, bv};
                const short8 b0 = *(const short8*)&sB2[((0 * NT + nt) * 64 + lane) * 8];
                acc = __builtin_amdgcn_mfma_f32_16x16x32_bf16(a2[0], b0, acc, 0, 0, 0);
                const short8 b1 = *(const short8*)&sB2[((1 * NT + nt) * 64 + lane) * 8];
                acc = __builtin_amdgcn_mfma_f32_16x16x32_bf16(a2[1], b1, acc, 0, 0, 0);
                #pragma unroll
                for (int r = 0; r < 4; ++r)
                    myH[(quad * 4 + r) * 72 + q2 * 16 + mrow] = (short)f2bf(acc[r]);
            }
            sv0[g] = *(const u32x4*)&myH[prow * 72 + pcol];
            sv1[g] = *(const u32x4*)&myH[(prow + 8) * 72 + pcol];
        }
        // clustered big store: each row's full extent in consecutive instrs
        if (fullgrp) {
            u16* const rb0 = big_out + (size_t)(nbase + prow) * NOUT + pcol;
            #pragma unroll
            for (int g = 0; g < NG; ++g)
                *(u32x4*)(rb0 + g * 64) = sv0[g];
            u16* const rb1 = big_out + (size_t)(nbase + prow + 8) * NOUT + pcol;
            #pragma unroll
            for (int g = 0; g < NG; ++g)
                *(u32x4*)(rb1 + g * 64) = sv1[g];
        } else {
            #pragma unroll
            for (int g = 0; g < NG; ++g) {
                const int nd0 = nbase + prow;
                if (nd0 < N)
                    *(u32x4*)(big_out + (size_t)nd0 * NOUT + g * 64 + pcol) = sv0[g];
                const int nd1 = nbase + prow + 8;
                if (nd1 < N)
                    *(u32x4*)(big_out + (size_t)nd1 * NOUT + g * 64 + pcol) = sv1[g];
            }
        }
    }
}

// -------- gather + softmax + gelu + MFMA-Wo + skip -------------------------
// Merged A-side + Q-side launch. One node per 8-lane group => 8 concurrent
// edge-chains/wave. r12: inner loop reverted to the r2 payload-prefetch-only
// form — the 2-deep K/V pipeline measured NEUTRAL-to-worse (r2 78.7 vs r11
// 80.8): FETCH is already compulsory-minimal (L3 absorbs re-reads), so the
// kernel is bounded by random 128-B granule throughput, which extra in-flight
// loads don't improve; clamped-tail reloads and rotation just add VALU.
struct GArgs {
    const int* cursor; const int2* payload; const u16* srcArr;
    const u16* qArr; const u16* h_in;
    const u16* Wof; const float* bo; const float* skip;
    u16* z_out;
    int qStride; int N; int ntiles; int t0; int t1;
};

__global__ __launch_bounds__(256, 8) void gather_finalize(
    GArgs A, GArgs Q, const float* __restrict__ p_rel)
{
    __shared__ __align__(16) short sG[4][16 * 72];     // per-wave gelu rows (bf16)
    __shared__ __align__(16) short sHh[4][16 * 72];    // per-wave h rows -> z rows

    const bool isA = (int)blockIdx.x < A.ntiles;
    const GArgs& G = isA ? A : Q;
    const int tile = isA ? (int)blockIdx.x : (int)blockIdx.x - A.ntiles;

    const int tid = threadIdx.x;
    const int wave = tid >> 6, lane = tid & 63;
    const int quad = lane >> 4, mrow = lane & 15;
    const int grp = lane >> 3;       // node group 0..7
    const int gl = lane & 7;         // lane within group; holds channels 8gl..8gl+7
    const int ghead = gl >> 2;       // head of this lane's channels
    const int prow = lane >> 3;      // store-phase row (8 rows/instr)
    const int pcol = (lane & 7) * 8; // 16-B chunk within 128-B row

    const float sk = sigmoidf_(G.skip[0]);
    const float isq = 0.17677669529663687f;   // 1/sqrt(32)
    const float s0 = p_rel[G.t0 * 2 + ghead] * isq;
    const float s1 = p_rel[G.t1 * 2 + ghead] * isq;

    short* const myG = &sG[wave][0];
    short* const myHh = &sHh[wave][0];

    const int N = G.N;
    const int nbase = tile * 64 + wave * 16;

    // hoisted in-degree loads for both subs (breaks cursor->payload hop)
    int cnt2[2];
    #pragma unroll
    for (int sub = 0; sub < 2; ++sub) {
        const int node = nbase + sub * 8 + grp;
        int c = (node < N && node < NQn) ? G.cursor[node] : 0;
        cnt2[sub] = (c > SLOTS) ? SLOTS : c;
    }

    #pragma unroll
    for (int sub = 0; sub < 2; ++sub) {
        const int nl = sub * 8 + grp;
        const int node = nbase + nl;
        const bool valid = node < N;
        const int cnt = cnt2[sub];
        uint4 qraw = make_uint4(0, 0, 0, 0), hraw = make_uint4(0, 0, 0, 0);
        if (valid) {
            qraw = *(const uint4*)(G.qArr + (size_t)node * G.qStride + gl * 8);
            hraw = *(const uint4*)(G.h_in + (size_t)node * 64 + gl * 8);
        }
        *(uint4*)&myHh[nl * 72 + gl * 8] = hraw;
        const float qv0 = bf2f_lo(qraw.x), qv1 = bf2f_hi(qraw.x);
        const float qv2 = bf2f_lo(qraw.y), qv3 = bf2f_hi(qraw.y);
        const float qv4 = bf2f_lo(qraw.z), qv5 = bf2f_hi(qraw.z);
        const float qv6 = bf2f_lo(qraw.w), qv7 = bf2f_hi(qraw.w);

        const int2* pp = G.payload + (size_t)node * SLOTS;
        float a0 = 0.f, a1 = 0.f, a2 = 0.f, a3 = 0.f;
        float a4 = 0.f, a5 = 0.f, a6 = 0.f, a7 = 0.f, den = 0.f;
        int2 e = make_int2(0, 0);
        if (cnt > 0) e = pp[0];
        for (int i = 0; i < cnt; ++i) {
            const int2 ec = e;
            if (i + 1 < cnt) e = pp[i + 1];      // prefetch: payload off critical path
            const int koff = ec.x & ~31;
            const uint4 kr = *(const uint4*)(G.srcArr + (size_t)koff + gl * 8);
            const uint4 vr = *(const uint4*)(G.srcArr + (size_t)koff + 64 + gl * 8);
            float p = qv0 * bf2f_lo(kr.x) + qv1 * bf2f_hi(kr.x)
                    + qv2 * bf2f_lo(kr.y) + qv3 * bf2f_hi(kr.y)
                    + qv4 * bf2f_lo(kr.z) + qv5 * bf2f_hi(kr.z)
                    + qv6 * bf2f_lo(kr.w) + qv7 * bf2f_hi(kr.w);
            p += __shfl_xor(p, 1);   // reduce over the 4 lanes of this head
            p += __shfl_xor(p, 2);
            const float sc = (ec.x & 1) ? s1 : s0;
            const float exv = __expf(p * sc);
            const float ew = exv * __int_as_float(ec.y);
            a0 = fmaf(ew, bf2f_lo(vr.x), a0); a1 = fmaf(ew, bf2f_hi(vr.x), a1);
            a2 = fmaf(ew, bf2f_lo(vr.y), a2); a3 = fmaf(ew, bf2f_hi(vr.y), a3);
            a4 = fmaf(ew, bf2f_lo(vr.z), a4); a5 = fmaf(ew, bf2f_hi(vr.z), a5);
            a6 = fmaf(ew, bf2f_lo(vr.w), a6); a7 = fmaf(ew, bf2f_hi(vr.w), a7);
            den += exv;
        }

        const float inv = 1.f / (den + 1e-16f);
        float gv[8] = {a0 * inv, a1 * inv, a2 * inv, a3 * inv,
                       a4 * inv, a5 * inv, a6 * inv, a7 * inv};
        #pragma unroll
        for (int j = 0; j < 8; ++j) {
            const float xx = gv[j];
            const float u = 0.7978845608028654f * (xx + 0.044715f * xx * xx * xx);
            const float th = 1.f - 2.f / (__expf(2.f * u) + 1.f);
            gv[j] = 0.5f * xx * (1.f + th);
        }
        uint4 gp;
        gp.x = (unsigned)f2bf(gv[0]) | ((unsigned)f2bf(gv[1]) << 16);
        gp.y = (unsigned)f2bf(gv[2]) | ((unsigned)f2bf(gv[3]) << 16);
        gp.z = (unsigned)f2bf(gv[4]) | ((unsigned)f2bf(gv[5]) << 16);
        gp.w = (unsigned)f2bf(gv[6]) | ((unsigned)f2bf(gv[7]) << 16);
        *(uint4*)&myG[nl * 72 + gl * 8] = gp;
    }

    // wave-private MFMA: Z16x64 = G16x64 @ Wo64x64 (+bo), skip blend -> myHh
    short8 ag[2];
    #pragma unroll
    for (int kt = 0; kt < 2; ++kt)
        ag[kt] = *(const short8*)&myG[mrow * 72 + kt * 32 + quad * 8];

    #pragma unroll
    for (int nt = 0; nt < 4; ++nt) {
        const float bov = G.bo[nt * 16 + mrow];
        f32x4 acc = {bov, bov, bov, bov};
        const short8 b0 = *(const short8*)&G.Wof[((0 * 4 + nt) * 64 + lane) * 8];
        acc = __builtin_amdgcn_mfma_f32_16x16x32_bf16(ag[0], b0, acc, 0, 0, 0);
        const short8 b1 = *(const short8*)&G.Wof[((1 * 4 + nt) * 64 + lane) * 8];
        acc = __builtin_amdgcn_mfma_f32_16x16x32_bf16(ag[1], b1, acc, 0, 0, 0);
        #pragma unroll
        for (int r = 0; r < 4; ++r) {
            const int row = quad * 4 + r;
            const int a = row * 72 + nt * 16 + mrow;
            const float hv = bf2f((u16)myHh[a]);
            myHh[a] = (short)f2bf(sk * acc[r] + (1.f - sk) * hv);
        }
    }

    // ---- z store: 2 back-to-back instrs, 2 KB contiguous ----
    if (nbase + 16 <= N) {
        const u32x4 w0 = *(const u32x4*)&myHh[prow * 72 + pcol];
        const u32x4 w1 = *(const u32x4*)&myHh[(prow + 8) * 72 + pcol];
        *(u32x4*)(G.z_out + (size_t)(nbase + prow) * 64 + pcol) = w0;
        *(u32x4*)(G.z_out + (size_t)(nbase + prow + 8) * 64 + pcol) = w1;
    } else {
        for (int e2 = lane; e2 < 16 * 64; e2 += 64) {
            const int r = e2 >> 6, c = e2 & 63;
            const int nd = nbase + r;
            if (nd < N) G.z_out[(size_t)nd * 64 + c] = (u16)myHh[r * 72 + c];
        }
    }
}

// -------- decoder: sigmoid(dot64) link prediction --------------------------
__global__ __launch_bounds__(256) void decoder_kernel(
    const u16* __restrict__ z_q, const u16* __restrict__ z_a,
    const int* __restrict__ pos_idx, const int* __restrict__ neg_idx,
    float* __restrict__ out)
{
    const int gid = blockIdx.x * 256 + threadIdx.x;
    const int o = gid >> 5;         // half-wave per output
    if (o >= 2 * NLn) return;
    const int lane = threadIdx.x & 31;
    const int* idx;
    int i;
    if (o < NLn) { idx = pos_idx; i = o; }
    else         { idx = neg_idx; i = o - NLn; }
    const int r0 = idx[i];
    const int r1 = idx[NLn + i];
    const unsigned uq = *(const unsigned*)(z_q + (size_t)r0 * 64 + 2 * lane);
    const unsigned ua = *(const unsigned*)(z_a + (size_t)r1 * 64 + 2 * lane);
    float s = bf2f_lo(uq) * bf2f_lo(ua) + bf2f_hi(uq) * bf2f_hi(ua);
    s += __shfl_xor(s, 16);
    s += __shfl_xor(s, 8);
    s += __shfl_xor(s, 4);
    s += __shfl_xor(s, 2);
    s += __shfl_xor(s, 1);
    if (lane == 0) out[o] = sigmoidf_(s);
}

extern "C" void kernel_launch(void* const* d_in, const int* in_sizes, int n_in,
                              void* d_out, int out_size, void* d_ws, size_t ws_size,
                              hipStream_t stream)
{
    (void)in_sizes; (void)n_in; (void)out_size;
    const float* x_q   = (const float*)d_in[0];
    const float* x_a   = (const float*)d_in[1];
    const int* ei_qca  = (const int*)d_in[2];
    const int* ei_qwa  = (const int*)d_in[3];
    const int* ei_rev  = (const int*)d_in[4];
    const int* pos_idx = (const int*)d_in[5];
    const int* neg_idx = (const int*)d_in[6];
    const float* w_qca = (const float*)d_in[7];
    const float* w_qwa = (const float*)d_in[8];
    const float* w_rev = (const float*)d_in[9];
    const float* W_in_q = (const float*)d_in[10]; const float* b_in_q = (const float*)d_in[11];
    const float* W_in_a = (const float*)d_in[12]; const float* b_in_a = (const float*)d_in[13];
    const float* Wk_qn = (const float*)d_in[14], *bk_qn = (const float*)d_in[15];
    const float* Wq_qn = (const float*)d_in[16], *bq_qn = (const float*)d_in[17];
    const float* Wv_qn = (const float*)d_in[18], *bv_qn = (const float*)d_in[19];
    const float* Wk_an = (const float*)d_in[20], *bk_an = (const float*)d_in[21];
    const float* Wq_an = (const float*)d_in[22], *bq_an = (const float*)d_in[23];
    const float* Wv_an = (const float*)d_in[24], *bv_an = (const float*)d_in[25];
    const float* a_rel = (const float*)d_in[26];
    const float* m_rel = (const float*)d_in[27];
    const float* p_rel = (const float*)d_in[28];
    const float* Wo_qn = (const float*)d_in[29], *bo_qn = (const float*)d_in[30];
    const float* Wo_an = (const float*)d_in[31], *bo_an = (const float*)d_in[32];
    const float* skip_qn = (const float*)d_in[33], *skip_an = (const float*)d_in[34];

    char* ws = (char*)d_ws;
    size_t off = 0;
    auto alloc = [&](size_t bytes) -> char* {
        char* p = ws + off;
        off = (off + bytes + 255) & ~(size_t)255;
        return p;
    };
    u16* big_q = (u16*)alloc((size_t)NQn * 320 * 2);  // q | k0 | v0 | k1 | v1
    u16* big_a = (u16*)alloc((size_t)NAn * 192 * 2);  // q | k2 | v2
    u16* h_q   = (u16*)alloc((size_t)NQn * 64 * 2);
    u16* h_a   = (u16*)alloc((size_t)NAn * 64 * 2);
    u16* z_q   = (u16*)alloc((size_t)NQn * 64 * 2);
    u16* z_a   = (u16*)alloc((size_t)NAn * 64 * 2);
    int2* payload_a = (int2*)alloc((size_t)NQn * SLOTS * 8);  // dst of E1/E2 < NQn
    int2* payload_q = (int2*)alloc((size_t)NQn * SLOTS * 8);
    char* zero_start = ws + off;
    int* cursor_a = (int*)alloc((size_t)NQn * 4);
    int* cursor_q = (int*)alloc((size_t)NQn * 4);
    char* zero_end = ws + off;
    u16* Wbigf_q = (u16*)alloc(64 * 320 * 2);
    float* bbig_q = (float*)alloc(320 * 4);
    u16* Wbigf_a = (u16*)alloc(64 * 192 * 2);
    float* bbig_a = (float*)alloc(192 * 4);
    u16* Wof_a = (u16*)alloc(4096 * 2);
    u16* Wof_q = (u16*)alloc(4096 * 2);
    u16* Winf_q = (u16*)alloc(8192 * 2);
    u16* Winf_a = (u16*)alloc(8192 * 2);

    if (off > ws_size) return;  // workspace too small: leave output zeroed (visible failure)

    hipMemsetAsync(zero_start, 0, (size_t)(zero_end - zero_start), stream);

    const int scatter_blocks = (E1n + E2n + E3n + 255) / 256;   // 3907
    prep_kernel<<<224 + scatter_blocks, 256, 0, stream>>>(
        Wk_qn, Wv_qn, Wq_qn, bk_qn, bv_qn, bq_qn,
        Wk_an, Wv_an, Wq_an, bk_an, bv_an, bq_an,
        a_rel, m_rel,
        Wbigf_q, bbig_q, Wbigf_a, bbig_a,
        W_in_q, Winf_q, W_in_a, Winf_a,
        Wo_an, Wof_a, Wo_qn, Wof_q,
        ei_qca, ei_qwa, ei_rev, w_qca, w_qwa, w_rev,
        cursor_a, cursor_q, payload_a, payload_q);

    node_mfma<320><<<512, 256, 0, stream>>>(x_q, NQn, Winf_q, b_in_q,
                                            Wbigf_q, bbig_q, h_q, big_q);
    node_mfma<192><<<768, 256, 0, stream>>>(x_a, NAn, Winf_a, b_in_a,
                                            Wbigf_a, bbig_a, h_a, big_a);

    // merged gather: blocks [0, ntA) = answer side, [ntA, ntA+ntQ) = question side
    const int ntA = (NAn + 63) >> 6;   // 3125
    const int ntQ = (NQn + 63) >> 6;   // 1563
    GArgs A, Q;
    A.cursor = cursor_a; A.payload = payload_a; A.srcArr = big_q;
    A.qArr = big_a; A.h_in = h_a; A.Wof = Wof_a; A.bo = bo_an; A.skip = skip_an;
    A.z_out = z_a; A.qStride = 192; A.N = NAn; A.ntiles = ntA; A.t0 = 0; A.t1 = 1;
    Q.cursor = cursor_q; Q.payload = payload_q; Q.srcArr = big_a;
    Q.qArr = big_q; Q.h_in = h_q; Q.Wof = Wof_q; Q.bo = bo_qn; Q.skip = skip_qn;
    Q.z_out = z_q; Q.qStride = 320; Q.N = NQn; Q.ntiles = ntQ; Q.t0 = 2; Q.t1 = 2;
    gather_finalize<<<ntA + ntQ, 256, 0, stream>>>(A, Q, p_rel);

    decoder_kernel<<<(2 * NLn * 32 + 255) / 256, 256, 0, stream>>>(
        z_q, z_a, pos_idx, neg_idx, (float*)d_out);
}